// Round 5
// baseline (409.158 us; speedup 1.0000x reference)
//
#include <hip/hip_runtime.h>
#include <hip/hip_bf16.h>

// Problem dims (fixed by setup_inputs): B=64, N=16384, D=1024, A=2048, H=8
#define NB 64
#define NN 16384
#define ND 1024
#define NA 2048
#define NH 8
#define KSPL 32     // k_post split-K chunks
#define NPL 8       // h_part planes (= NA/256 n-blocks of k_c1h)
#define NT 16       // k_c1h K-tiles (ND/64)

typedef __attribute__((ext_vector_type(4))) float f32x4;
typedef __attribute__((ext_vector_type(8))) short short8;
typedef __attribute__((ext_vector_type(8))) unsigned short ushort8;

__device__ __forceinline__ unsigned short f2bf(float f) {
    unsigned int u = __float_as_uint(f);
    u = (u + 0x7fff + ((u >> 16) & 1)) >> 16;   // round-to-nearest-even
    return (unsigned short)u;
}

__device__ __forceinline__ float bf2f(unsigned short s) {
    return __uint_as_float((unsigned int)s << 16);
}

__device__ __forceinline__ void load_lds16(const void* g, void* l) {
    __builtin_amdgcn_global_load_lds((const __attribute__((address_space(1))) void*)g,
                                     (__attribute__((address_space(3))) void*)l, 16, 0, 0);
}

// ---- k_pre: segoff + cast x->xb + cast/transpose w1->w1t + zero out (atomic tgt)
__global__ __launch_bounds__(256) void k_pre(const float* __restrict__ x,
                                             const float* __restrict__ w1,
                                             const int* __restrict__ segnum,
                                             unsigned short* __restrict__ xb,
                                             unsigned short* __restrict__ w1t,
                                             int* __restrict__ segoff,
                                             float* __restrict__ outz) {
    __shared__ unsigned short t[32][33];
    const int bx = blockIdx.x;
    if (bx < 8192) {
        size_t i = ((size_t)bx * 256 + threadIdx.x) * 8;
        float4 a = *(const float4*)(x + i);
        float4 b = *(const float4*)(x + i + 4);
        ushort8 o;
        o[0] = f2bf(a.x); o[1] = f2bf(a.y); o[2] = f2bf(a.z); o[3] = f2bf(a.w);
        o[4] = f2bf(b.x); o[5] = f2bf(b.y); o[6] = f2bf(b.z); o[7] = f2bf(b.w);
        *(ushort8*)(xb + i) = o;
    } else if (bx < 10240) {
        const int idx = bx - 8192;                 // 0..2047
        const int a0 = (idx & 63) * 32, d0 = (idx >> 6) * 32;
        const int tx = threadIdx.x & 31, ty4 = (threadIdx.x >> 5) * 4;
#pragma unroll
        for (int i = 0; i < 4; i++)
            t[tx][ty4 + i] = f2bf(w1[(size_t)(d0 + ty4 + i) * NA + a0 + tx]);
        __syncthreads();
#pragma unroll
        for (int i = 0; i < 4; i++)
            w1t[(size_t)(a0 + ty4 + i) * ND + d0 + tx] = t[ty4 + i][tx];
    } else if (bx < 10256) {
        // zero the atomic-accumulated out region [NB*ND]
        const int i = ((bx - 10240) * 256 + threadIdx.x) * 16;
        float4 z = make_float4(0.f, 0.f, 0.f, 0.f);
        *(float4*)(outz + i)      = z;
        *(float4*)(outz + i + 4)  = z;
        *(float4*)(outz + i + 8)  = z;
        *(float4*)(outz + i + 12) = z;
    } else {
        if (threadIdx.x == 0) {
            int a = 0;
            segoff[0] = 0;
            for (int b = 0; b < NB; b++) { a += segnum[b]; segoff[b + 1] = a; }
        }
    }
}

// --- k_c1h v3 (measured best, 71.9us): 256x256 tile, BK=64, 8 waves (2Mx4N),
// 4-phase/K-tile, B frags register-resident (24 ds_read_b128/K-tile/wave).
//   p0 (ks0,mu0): load B[4][ks0] + A[mu0][ks0]; stage A1,B1 of t+1
//   p1 (ks0,mu1): load A[mu1][ks0]
//   p2 (ks1,mu0): load B[4][ks1] + A[mu0][ks1]
//   p3 (ks1,mu1): load A[mu1][ks1]; stage A0,B0 of t+2; vmcnt(4)
// Hazard invariants as audited R1-R3. XCD-chunked swizzle (bijective, 512%8==0).
__global__ __launch_bounds__(512, 2) void k_c1h(const unsigned short* __restrict__ xb,
                                                const unsigned short* __restrict__ w1t,
                                                const float* __restrict__ w2,
                                                float* __restrict__ h_part) {
    __shared__ unsigned short SM[73984];           // 147968 B
    unsigned short* As   = SM;                     // [2 dbuf][2 half][128*64]
    unsigned short* Bs   = SM + 32768;             // same layout
    unsigned short* w2hi = SM + 65536;             // [16][264], rows 8..15 zero
    unsigned short* w2lo = SM + 69760;

    const int tid = threadIdx.x;
    const int wv = tid >> 6, lane = tid & 63;
    const int wm = wv >> 2, wn = wv & 3;           // 2 x 4 wave grid
    const int quad = lane >> 4, lc = lane & 15;
    const int l7 = lc & 7;

    const int wg = blockIdx.x + blockIdx.y * (NN / 256);
    const int swz = (wg & 7) * 64 + (wg >> 3);
    const int bxm = swz & 63, byn = swz >> 6;
    const int m0 = bxm * 256, n0 = byn * 256;

    // stage w2 slice -> transposed bf16 hi/lo planes [q][k], k in [0,256)
    for (int i = tid; i < 4224; i += 512) { w2hi[i] = 0; w2lo[i] = 0; }
    for (int i = tid; i < 2048; i += 512) {
        int k = i >> 3, q = i & 7;
        float w = w2[(size_t)(n0 + k) * NH + q];
        unsigned short hi = f2bf(w);
        w2hi[q * 264 + k] = hi;
        w2lo[q * 264 + k] = f2bf(w - bf2f(hi));
    }

    // staging constants: global source pre-swizzled, LDS linear (G21).
    const int rr = wv * 8 + (lane >> 3);
    const size_t goff0 = (size_t)rr * ND + (size_t)(((lane & 7) ^ (lane >> 3)) << 3);
    const size_t goff1 = goff0 + (size_t)64 * ND;  // j=1: rows +64
    const int ls0 = wv * 512, ls1 = (wv + 8) * 512;

    const unsigned short* xA = xb  + (size_t)m0 * ND;
    const unsigned short* xB = w1t + (size_t)n0 * ND;

#define STAGE(SRC, DST) do { \
        load_lds16((SRC) + goff0, (DST) + ls0); \
        load_lds16((SRC) + goff1, (DST) + ls1); } while (0)

    f32x4 acc[8][4];
#pragma unroll
    for (int i = 0; i < 8; i++)
#pragma unroll
        for (int j = 0; j < 4; j++) acc[i][j] = (f32x4){0.f, 0.f, 0.f, 0.f};

    // ds_read row offsets (row&7 == lc&7 for all fragments)
    int aoff[4], boff[2];
#pragma unroll
    for (int i = 0; i < 4; i++) aoff[i] = (wm * 64 + i * 16 + lc) * 64;
#pragma unroll
    for (int i = 0; i < 2; i++) boff[i] = (wn * 32 + i * 16 + lc) * 64;

    short8 bfr[4];   // B frags, register-resident across each (ks) phase pair

#define PHASE(D, KS, MU, LOADB, STAGES, WAIT2)                                   \
    do {                                                                         \
        const unsigned short* Ab = As + ((D) * 2 + (MU)) * 8192;                 \
        const unsigned short* Bb = Bs + ((D) * 2) * 8192;                        \
        const int kb = ((((KS) * 4) + quad) ^ l7) << 3;                          \
        short8 af[4];                                                            \
        _Pragma("unroll") for (int i = 0; i < 4; i++)                            \
            af[i] = *(const short8*)&Ab[aoff[i] + kb];                           \
        if (LOADB) {                                                             \
            _Pragma("unroll") for (int j = 0; j < 2; j++) {                      \
                bfr[j]     = *(const short8*)&Bb[boff[j] + kb];                  \
                bfr[2 + j] = *(const short8*)&Bb[8192 + boff[j] + kb];           \
            }                                                                    \
        }                                                                        \
        STAGES;                                                                  \
        asm volatile("" ::: "memory");                                           \
        __builtin_amdgcn_s_barrier();                                            \
        asm volatile("" ::: "memory");                                           \
        __builtin_amdgcn_s_setprio(1);                                           \
        _Pragma("unroll") for (int i = 0; i < 4; i++)                            \
            _Pragma("unroll") for (int j = 0; j < 4; j++)                        \
                acc[(MU) * 4 + i][j] = __builtin_amdgcn_mfma_f32_16x16x32_bf16(  \
                    af[i], bfr[j], acc[(MU) * 4 + i][j], 0, 0, 0);               \
        __builtin_amdgcn_s_setprio(0);                                           \
        WAIT2;                                                                   \
        asm volatile("" ::: "memory");                                           \
        __builtin_amdgcn_s_barrier();                                            \
        asm volatile("" ::: "memory");                                           \
    } while (0)

    // prologue: tile0 full (A0,B0,A1,B1) + tile1 A0,B0; allow newest 4 in flight
    STAGE(xA, As);                                  // A0(0)
    STAGE(xB, Bs);                                  // B0(0)
    STAGE(xA + (size_t)128 * ND, As + 8192);        // A1(0)
    STAGE(xB + (size_t)128 * ND, Bs + 8192);        // B1(0)
    STAGE(xA + 64, As + 16384);                     // A0(1)
    STAGE(xB + 64, Bs + 16384);                     // B0(1)
    asm volatile("s_waitcnt vmcnt(4)" ::: "memory");
    __builtin_amdgcn_s_barrier();
    asm volatile("" ::: "memory");

#pragma unroll 2
    for (int t = 0; t < NT - 2; t++) {
        const int d = t & 1;
        const unsigned short* xAn = xA + (t + 1) * 64;
        const unsigned short* xBn = xB + (t + 1) * 64;
        const unsigned short* xAnn = xA + (t + 2) * 64;
        const unsigned short* xBnn = xB + (t + 2) * 64;
        unsigned short* Ad1 = As + ((d ^ 1) * 2) * 8192;   // buf of tile t+1
        unsigned short* Bd1 = Bs + ((d ^ 1) * 2) * 8192;
        unsigned short* Ad2 = As + (d * 2) * 8192;         // buf of tile t+2
        unsigned short* Bd2 = Bs + (d * 2) * 8192;
        PHASE(d, 0, 0, 1,
              { STAGE(xAn + (size_t)128 * ND, Ad1 + 8192);
                STAGE(xBn + (size_t)128 * ND, Bd1 + 8192); }, {});
        PHASE(d, 0, 1, 0, {}, {});
        PHASE(d, 1, 0, 1, {}, {});
        PHASE(d, 1, 1, 0,
              { STAGE(xAnn, Ad2); STAGE(xBnn, Bd2); },
              { asm volatile("s_waitcnt vmcnt(4)" ::: "memory"); });
    }
    {   // t = NT-2 (d=0): stage only A1/B1 of last tile; drain before it
        const unsigned short* xAn = xA + (NT - 1) * 64;
        const unsigned short* xBn = xB + (NT - 1) * 64;
        PHASE(0, 0, 0, 1,
              { STAGE(xAn + (size_t)128 * ND, As + 3 * 8192);
                STAGE(xBn + (size_t)128 * ND, Bs + 3 * 8192); }, {});
        PHASE(0, 0, 1, 0, {}, {});
        PHASE(0, 1, 0, 1, {}, {});
        PHASE(0, 1, 1, 0, {}, { asm volatile("s_waitcnt vmcnt(0)" ::: "memory"); });
    }
    // t = NT-1 (d=1): pure compute
    PHASE(1, 0, 0, 1, {}, {});
    PHASE(1, 0, 1, 0, {}, {});
    PHASE(1, 1, 0, 1, {}, {});
    PHASE(1, 1, 1, 0, {}, {});

#undef PHASE
#undef STAGE

    // ---- epilogue: h[m,q] += relu(c1) @ w2, two 128-col passes reusing LDS
    unsigned short* c1s = SM;                      // [256][136] (69632 B)
    f32x4 hacc[2];
    hacc[0] = (f32x4){0.f, 0.f, 0.f, 0.f};
    hacc[1] = (f32x4){0.f, 0.f, 0.f, 0.f};

#pragma unroll
    for (int nu = 0; nu < 2; nu++) {
#pragma unroll
        for (int mi = 0; mi < 8; mi++) {
            const int row = (mi >> 2) * 128 + wm * 64 + (mi & 3) * 16 + quad * 4;
#pragma unroll
            for (int nj = 0; nj < 2; nj++) {
                const int col = wn * 32 + nj * 16 + lc;        // local 0..127
                const int ni = nu * 2 + nj;
#pragma unroll
                for (int r = 0; r < 4; r++)
                    c1s[(row + r) * 136 + col] = f2bf(fmaxf(acc[mi][ni][r], 0.f));
            }
        }
        asm volatile("s_waitcnt lgkmcnt(0)" ::: "memory");
        __builtin_amdgcn_s_barrier();
        asm volatile("" ::: "memory");
        // wave handles rows wv*32..+31; K = 128 local cols, hi+lo w2
#pragma unroll
        for (int ks = 0; ks < 4; ks++) {
            short8 bh = *(const short8*)&w2hi[lc * 264 + nu * 128 + ks * 32 + quad * 8];
            short8 bl = *(const short8*)&w2lo[lc * 264 + nu * 128 + ks * 32 + quad * 8];
#pragma unroll
            for (int mt = 0; mt < 2; mt++) {
                short8 afr = *(const short8*)&c1s[(wv * 32 + mt * 16 + lc) * 136 +
                                                  ks * 32 + quad * 8];
                hacc[mt] = __builtin_amdgcn_mfma_f32_16x16x32_bf16(afr, bh, hacc[mt], 0, 0, 0);
                hacc[mt] = __builtin_amdgcn_mfma_f32_16x16x32_bf16(afr, bl, hacc[mt], 0, 0, 0);
            }
        }
        asm volatile("" ::: "memory");
        __builtin_amdgcn_s_barrier();
        asm volatile("" ::: "memory");
    }

    if (lc < NH) {
        float* hp = h_part + (size_t)byn * (NN * NH);
#pragma unroll
        for (int mt = 0; mt < 2; mt++)
#pragma unroll
            for (int r = 0; r < 4; r++)
                hp[(size_t)(m0 + wv * 32 + mt * 16 + quad * 4 + r) * NH + lc] = hacc[mt][r];
    }
}

// --------- k_fuse: per-segment softmax (attn in LDS, never global) + gram
//           + bdh[b] = x^T attn + out_segment. 64 blocks x 512 threads.
// len <= 1024 guaranteed by setup (max ~455).
__global__ __launch_bounds__(512) void k_fuse(const float* __restrict__ h_part,
                                              const unsigned short* __restrict__ xb,
                                              const int* __restrict__ segoff,
                                              float* __restrict__ bdh,
                                              float* __restrict__ out_segment,
                                              float* __restrict__ gram) {
    const int b = blockIdx.x;
    const int s0 = segoff[b], s1 = segoff[b + 1];
    const int len = s1 - s0;
    const int tid = threadIdx.x;
    const int wv = tid >> 6;
    __shared__ float hl[1024 * NH];      // 32KB: h sums, then attn in place
    __shared__ float red[8][NH];
    __shared__ float mb[NH];
    __shared__ float sinv[NH];
    __shared__ float gred[8][64];

    float mx[NH];
#pragma unroll
    for (int q = 0; q < NH; q++) mx[q] = -1e30f;

    // pass 1: sum planes -> hl, max
    for (int n = s0 + tid; n < s1; n += 512) {
        float v[NH];
#pragma unroll
        for (int q = 0; q < NH; q++) v[q] = 0.f;
#pragma unroll
        for (int p = 0; p < NPL; p++) {
            const float4* hp = (const float4*)(h_part + (size_t)p * (NN * NH) + (size_t)n * NH);
            float4 u0 = hp[0], u1 = hp[1];
            v[0] += u0.x; v[1] += u0.y; v[2] += u0.z; v[3] += u0.w;
            v[4] += u1.x; v[5] += u1.y; v[6] += u1.z; v[7] += u1.w;
        }
#pragma unroll
        for (int q = 0; q < NH; q++) {
            hl[(n - s0) * NH + q] = v[q];
            mx[q] = fmaxf(mx[q], v[q]);
        }
    }
#pragma unroll
    for (int q = 0; q < NH; q++)
        for (int o = 1; o < 64; o <<= 1) mx[q] = fmaxf(mx[q], __shfl_xor(mx[q], o));
    if ((tid & 63) == 0)
        for (int q = 0; q < NH; q++) red[wv][q] = mx[q];
    __syncthreads();
    if (tid < NH) {
        float m = red[0][tid];
#pragma unroll
        for (int w = 1; w < 8; w++) m = fmaxf(m, red[w][tid]);
        mb[tid] = m;
    }
    __syncthreads();

    // pass 2: sum of exp (from hl)
    float sm[NH];
#pragma unroll
    for (int q = 0; q < NH; q++) sm[q] = 0.f;
    for (int n = s0 + tid; n < s1; n += 512) {
#pragma unroll
        for (int q = 0; q < NH; q++) sm[q] += expf(hl[(n - s0) * NH + q] - mb[q]);
    }
#pragma unroll
    for (int q = 0; q < NH; q++)
        for (int o = 1; o < 64; o <<= 1) sm[q] += __shfl_xor(sm[q], o);
    if ((tid & 63) == 0)
        for (int q = 0; q < NH; q++) red[wv][q] = sm[q];
    __syncthreads();
    if (tid < NH) {
        float s = red[0][tid];
#pragma unroll
        for (int w = 1; w < 8; w++) s += red[w][tid];
        sinv[tid] = 1.0f / s;
    }
    __syncthreads();

    // pass 3: attn in place + gram accumulate
    float g[NH][NH];
#pragma unroll
    for (int i = 0; i < NH; i++)
#pragma unroll
        for (int j = 0; j < NH; j++) g[i][j] = 0.f;

    for (int n = s0 + tid; n < s1; n += 512) {
        float a[NH];
#pragma unroll
        for (int q = 0; q < NH; q++) {
            a[q] = expf(hl[(n - s0) * NH + q] - mb[q]) * sinv[q];
            hl[(n - s0) * NH + q] = a[q];
        }
#pragma unroll
        for (int i = 0; i < NH; i++)
#pragma unroll
            for (int j = 0; j < NH; j++) g[i][j] += a[i] * a[j];
    }
#pragma unroll
    for (int i = 0; i < NH; i++)
#pragma unroll
        for (int j = 0; j < NH; j++)
            for (int o = 1; o < 64; o <<= 1) g[i][j] += __shfl_xor(g[i][j], o);
    if ((tid & 63) == 0) {
#pragma unroll
        for (int i = 0; i < NH; i++)
#pragma unroll
            for (int j = 0; j < NH; j++) gred[wv][i * NH + j] = g[i][j];
    }
    __syncthreads();                     // gred ready AND hl (attn) stable
    if (tid < 64) {
        float s = gred[0][tid];
#pragma unroll
        for (int w = 1; w < 8; w++) s += gred[w][tid];
        gram[(size_t)b * 64 + tid] = s;
    }

    // phase B: bdh[b,d,h] = sum_n x[n,d]*attn[n,h]; out_segment = mean(x)
    const int d0 = tid * 2;              // 2 d-cols per thread
    float acc0[NH], acc1[NH];
    float xs0 = 0.f, xs1 = 0.f;
#pragma unroll
    for (int q = 0; q < NH; q++) { acc0[q] = 0.f; acc1[q] = 0.f; }

    const unsigned short* xp = xb + (size_t)s0 * ND + d0;
#pragma unroll 2
    for (int n = 0; n < len; n++) {
        const float* ap = &hl[n * NH];
        float4 a0 = *(const float4*)ap;
        float4 a1 = *(const float4*)(ap + 4);
        unsigned int xv = *(const unsigned int*)(xp + (size_t)n * ND);
        float x0 = bf2f((unsigned short)(xv & 0xffffu));
        float x1 = bf2f((unsigned short)(xv >> 16));
        xs0 += x0; xs1 += x1;
        float aq[NH] = {a0.x, a0.y, a0.z, a0.w, a1.x, a1.y, a1.z, a1.w};
#pragma unroll
        for (int q = 0; q < NH; q++) {
            acc0[q] += x0 * aq[q];
            acc1[q] += x1 * aq[q];
        }
    }
    float* bp = bdh + (size_t)b * (ND * NH) + (size_t)d0 * NH;
    *(float4*)(bp + 0)  = make_float4(acc0[0], acc0[1], acc0[2], acc0[3]);
    *(float4*)(bp + 4)  = make_float4(acc0[4], acc0[5], acc0[6], acc0[7]);
    *(float4*)(bp + 8)  = make_float4(acc1[0], acc1[1], acc1[2], acc1[3]);
    *(float4*)(bp + 12) = make_float4(acc1[4], acc1[5], acc1[6], acc1[7]);
    const float il = 1.0f / (float)len;
    out_segment[(size_t)b * ND + d0]     = xs0 * il;
    out_segment[(size_t)b * ND + d0 + 1] = xs1 * il;
}

// --------------- out += bdh[64,8192] @ w_post chunk (split-K, atomic epilogue)
__global__ __launch_bounds__(256) void k_post(const float* __restrict__ bdh,
                                              const float* __restrict__ wp,
                                              float* __restrict__ out) {
    __shared__ float as[32][68];
    __shared__ float bs[32][128];
    const int tid = threadIdx.x;
    const int n0 = blockIdx.x * 128;
    const int k0 = blockIdx.y * (8192 / KSPL);
    const int tr = tid >> 4, tc = tid & 15;

    float acc[4][8];
#pragma unroll
    for (int i = 0; i < 4; i++)
#pragma unroll
        for (int j = 0; j < 8; j++) acc[i][j] = 0.f;

    for (int kc = 0; kc < 8192 / KSPL; kc += 32) {
        __syncthreads();
        {
            int r = tid >> 2;
            int c = (tid & 3) * 8;
            const float4* gp = (const float4*)(bdh + (size_t)r * (ND * NH) + k0 + kc + c);
            float4 v0 = gp[0], v1 = gp[1];
            as[c + 0][r] = v0.x; as[c + 1][r] = v0.y; as[c + 2][r] = v0.z; as[c + 3][r] = v0.w;
            as[c + 4][r] = v1.x; as[c + 5][r] = v1.y; as[c + 6][r] = v1.z; as[c + 7][r] = v1.w;
        }
        {
            int r = tid >> 3;
            int c = (tid & 7) * 16;
            const float4* gp = (const float4*)(wp + (size_t)(k0 + kc + r) * ND + n0 + c);
            float4* sp = (float4*)&bs[r][c];
            sp[0] = gp[0]; sp[1] = gp[1]; sp[2] = gp[2]; sp[3] = gp[3];
        }
        __syncthreads();
#pragma unroll
        for (int k = 0; k < 32; k++) {
            float4 a  = *(const float4*)&as[k][tr * 4];
            float4 b0 = *(const float4*)&bs[k][tc * 8];
            float4 b1 = *(const float4*)&bs[k][tc * 8 + 4];
            float av[4] = {a.x, a.y, a.z, a.w};
            float bv[8] = {b0.x, b0.y, b0.z, b0.w, b1.x, b1.y, b1.z, b1.w};
#pragma unroll
            for (int i = 0; i < 4; i++)
#pragma unroll
                for (int j = 0; j < 8; j++) acc[i][j] += av[i] * bv[j];
        }
    }

#pragma unroll
    for (int i = 0; i < 4; i++)
#pragma unroll
        for (int j = 0; j < 8; j++)
            atomicAdd(&out[(size_t)(tr * 4 + i) * ND + n0 + tc * 8 + j], acc[i][j]);
}

extern "C" void kernel_launch(void* const* d_in, const int* in_sizes, int n_in,
                              void* d_out, int out_size, void* d_ws, size_t ws_size,
                              hipStream_t stream) {
    (void)in_sizes; (void)n_in; (void)out_size; (void)ws_size;
    const float* x      = (const float*)d_in[0];
    const int*   segnum = (const int*)d_in[1];
    const float* w1     = (const float*)d_in[2];
    const float* w2     = (const float*)d_in[3];
    const float* wpost  = (const float*)d_in[4];

    float* out         = (float*)d_out;            // [64*1024] (atomic-accumulated)
    float* out_segment = out + NB * ND;            // [64*1024]
    float* gram        = out + 2 * NB * ND;        // [64*64]

    char* ws = (char*)d_ws;
    const size_t MB = 1024 * 1024;
    int*   segoff   = (int*)ws;                                    // 1KB   @0
    float* bdh      = (float*)(ws + 2 * MB);                       // 2MB   @2MB
    float* h_part   = (float*)(ws + 4 * MB);                       // 4MB   @4MB (8 planes)
    unsigned short* xb  = (unsigned short*)(ws + 12 * MB);         // 32MB  @12MB
    unsigned short* w1t = (unsigned short*)(ws + 44 * MB);         // 4MB   @44MB

    k_pre<<<10257, 256, 0, stream>>>(x, w1, segnum, xb, w1t, segoff, out);
    k_c1h<<<dim3(NN / 256, NA / 256), 512, 0, stream>>>(xb, w1t, w2, h_part);
    k_fuse<<<NB, 512, 0, stream>>>(h_part, xb, segoff, bdh, out_segment, gram);
    k_post<<<dim3(ND / 128, KSPL), 256, 0, stream>>>(bdh, wpost, out);
}

// Round 7
// 283.754 us; speedup vs baseline: 1.4419x; 1.4419x over previous
//
#include <hip/hip_runtime.h>
#include <hip/hip_bf16.h>

// Problem dims (fixed by setup_inputs): B=64, N=16384, D=1024, A=2048, H=8
#define NB 64
#define NN 16384
#define ND 1024
#define NA 2048
#define NH 8
#define KSPL 32     // k_post split-K chunks
#define NPL 8       // h_part planes (= NA/256 n-blocks of k_c1h)
#define NT 16       // k_c1h K-tiles (ND/64)

typedef __attribute__((ext_vector_type(4))) float f32x4;
typedef __attribute__((ext_vector_type(8))) short short8;
typedef __attribute__((ext_vector_type(8))) unsigned short ushort8;

__device__ __forceinline__ unsigned short f2bf(float f) {
    unsigned int u = __float_as_uint(f);
    u = (u + 0x7fff + ((u >> 16) & 1)) >> 16;   // round-to-nearest-even
    return (unsigned short)u;
}

__device__ __forceinline__ float bf2f(unsigned short s) {
    return __uint_as_float((unsigned int)s << 16);
}

__device__ __forceinline__ void load_lds16(const void* g, void* l) {
    __builtin_amdgcn_global_load_lds((const __attribute__((address_space(1))) void*)g,
                                     (__attribute__((address_space(3))) void*)l, 16, 0, 0);
}

// ---- k_pre: segoff + cast x->xb + cast/transpose w1->w1t
__global__ __launch_bounds__(256) void k_pre(const float* __restrict__ x,
                                             const float* __restrict__ w1,
                                             const int* __restrict__ segnum,
                                             unsigned short* __restrict__ xb,
                                             unsigned short* __restrict__ w1t,
                                             int* __restrict__ segoff) {
    __shared__ unsigned short t[32][33];
    const int bx = blockIdx.x;
    if (bx < 8192) {
        size_t i = ((size_t)bx * 256 + threadIdx.x) * 8;
        float4 a = *(const float4*)(x + i);
        float4 b = *(const float4*)(x + i + 4);
        ushort8 o;
        o[0] = f2bf(a.x); o[1] = f2bf(a.y); o[2] = f2bf(a.z); o[3] = f2bf(a.w);
        o[4] = f2bf(b.x); o[5] = f2bf(b.y); o[6] = f2bf(b.z); o[7] = f2bf(b.w);
        *(ushort8*)(xb + i) = o;
    } else if (bx < 10240) {
        const int idx = bx - 8192;                 // 0..2047
        const int a0 = (idx & 63) * 32, d0 = (idx >> 6) * 32;
        const int tx = threadIdx.x & 31, ty4 = (threadIdx.x >> 5) * 4;
#pragma unroll
        for (int i = 0; i < 4; i++)
            t[tx][ty4 + i] = f2bf(w1[(size_t)(d0 + ty4 + i) * NA + a0 + tx]);
        __syncthreads();
#pragma unroll
        for (int i = 0; i < 4; i++)
            w1t[(size_t)(a0 + ty4 + i) * ND + d0 + tx] = t[ty4 + i][tx];
    } else {
        if (threadIdx.x == 0) {
            int a = 0;
            segoff[0] = 0;
            for (int b = 0; b < NB; b++) { a += segnum[b]; segoff[b + 1] = a; }
        }
    }
}

// --- k_c1h v3 (measured best, 71.9us): 256x256 tile, BK=64, 8 waves (2Mx4N),
// 4-phase/K-tile, B frags register-resident (24 ds_read_b128/K-tile/wave).
// Hazard invariants as audited R1-R3. XCD-chunked swizzle (bijective, 512%8==0).
__global__ __launch_bounds__(512, 2) void k_c1h(const unsigned short* __restrict__ xb,
                                                const unsigned short* __restrict__ w1t,
                                                const float* __restrict__ w2,
                                                float* __restrict__ h_part) {
    __shared__ unsigned short SM[73984];           // 147968 B
    unsigned short* As   = SM;                     // [2 dbuf][2 half][128*64]
    unsigned short* Bs   = SM + 32768;             // same layout
    unsigned short* w2hi = SM + 65536;             // [16][264], rows 8..15 zero
    unsigned short* w2lo = SM + 69760;

    const int tid = threadIdx.x;
    const int wv = tid >> 6, lane = tid & 63;
    const int wm = wv >> 2, wn = wv & 3;           // 2 x 4 wave grid
    const int quad = lane >> 4, lc = lane & 15;
    const int l7 = lc & 7;

    const int wg = blockIdx.x + blockIdx.y * (NN / 256);
    const int swz = (wg & 7) * 64 + (wg >> 3);
    const int bxm = swz & 63, byn = swz >> 6;
    const int m0 = bxm * 256, n0 = byn * 256;

    // stage w2 slice -> transposed bf16 hi/lo planes [q][k], k in [0,256)
    for (int i = tid; i < 4224; i += 512) { w2hi[i] = 0; w2lo[i] = 0; }
    for (int i = tid; i < 2048; i += 512) {
        int k = i >> 3, q = i & 7;
        float w = w2[(size_t)(n0 + k) * NH + q];
        unsigned short hi = f2bf(w);
        w2hi[q * 264 + k] = hi;
        w2lo[q * 264 + k] = f2bf(w - bf2f(hi));
    }

    // staging constants: global source pre-swizzled, LDS linear (G21).
    const int rr = wv * 8 + (lane >> 3);
    const size_t goff0 = (size_t)rr * ND + (size_t)(((lane & 7) ^ (lane >> 3)) << 3);
    const size_t goff1 = goff0 + (size_t)64 * ND;  // j=1: rows +64
    const int ls0 = wv * 512, ls1 = (wv + 8) * 512;

    const unsigned short* xA = xb  + (size_t)m0 * ND;
    const unsigned short* xB = w1t + (size_t)n0 * ND;

#define STAGE(SRC, DST) do { \
        load_lds16((SRC) + goff0, (DST) + ls0); \
        load_lds16((SRC) + goff1, (DST) + ls1); } while (0)

    f32x4 acc[8][4];
#pragma unroll
    for (int i = 0; i < 8; i++)
#pragma unroll
        for (int j = 0; j < 4; j++) acc[i][j] = (f32x4){0.f, 0.f, 0.f, 0.f};

    // ds_read row offsets (row&7 == lc&7 for all fragments)
    int aoff[4], boff[2];
#pragma unroll
    for (int i = 0; i < 4; i++) aoff[i] = (wm * 64 + i * 16 + lc) * 64;
#pragma unroll
    for (int i = 0; i < 2; i++) boff[i] = (wn * 32 + i * 16 + lc) * 64;

    short8 bfr[4];   // B frags, register-resident across each (ks) phase pair

#define PHASE(D, KS, MU, LOADB, STAGES, WAIT2)                                   \
    do {                                                                         \
        const unsigned short* Ab = As + ((D) * 2 + (MU)) * 8192;                 \
        const unsigned short* Bb = Bs + ((D) * 2) * 8192;                        \
        const int kb = ((((KS) * 4) + quad) ^ l7) << 3;                          \
        short8 af[4];                                                            \
        _Pragma("unroll") for (int i = 0; i < 4; i++)                            \
            af[i] = *(const short8*)&Ab[aoff[i] + kb];                           \
        if (LOADB) {                                                             \
            _Pragma("unroll") for (int j = 0; j < 2; j++) {                      \
                bfr[j]     = *(const short8*)&Bb[boff[j] + kb];                  \
                bfr[2 + j] = *(const short8*)&Bb[8192 + boff[j] + kb];           \
            }                                                                    \
        }                                                                        \
        STAGES;                                                                  \
        asm volatile("" ::: "memory");                                           \
        __builtin_amdgcn_s_barrier();                                            \
        asm volatile("" ::: "memory");                                           \
        __builtin_amdgcn_s_setprio(1);                                           \
        _Pragma("unroll") for (int i = 0; i < 4; i++)                            \
            _Pragma("unroll") for (int j = 0; j < 4; j++)                        \
                acc[(MU) * 4 + i][j] = __builtin_amdgcn_mfma_f32_16x16x32_bf16(  \
                    af[i], bfr[j], acc[(MU) * 4 + i][j], 0, 0, 0);               \
        __builtin_amdgcn_s_setprio(0);                                           \
        WAIT2;                                                                   \
        asm volatile("" ::: "memory");                                           \
        __builtin_amdgcn_s_barrier();                                            \
        asm volatile("" ::: "memory");                                           \
    } while (0)

    // prologue: tile0 full (A0,B0,A1,B1) + tile1 A0,B0; allow newest 4 in flight
    STAGE(xA, As);                                  // A0(0)
    STAGE(xB, Bs);                                  // B0(0)
    STAGE(xA + (size_t)128 * ND, As + 8192);        // A1(0)
    STAGE(xB + (size_t)128 * ND, Bs + 8192);        // B1(0)
    STAGE(xA + 64, As + 16384);                     // A0(1)
    STAGE(xB + 64, Bs + 16384);                     // B0(1)
    asm volatile("s_waitcnt vmcnt(4)" ::: "memory");
    __builtin_amdgcn_s_barrier();
    asm volatile("" ::: "memory");

#pragma unroll 2
    for (int t = 0; t < NT - 2; t++) {
        const int d = t & 1;
        const unsigned short* xAn = xA + (t + 1) * 64;
        const unsigned short* xBn = xB + (t + 1) * 64;
        const unsigned short* xAnn = xA + (t + 2) * 64;
        const unsigned short* xBnn = xB + (t + 2) * 64;
        unsigned short* Ad1 = As + ((d ^ 1) * 2) * 8192;   // buf of tile t+1
        unsigned short* Bd1 = Bs + ((d ^ 1) * 2) * 8192;
        unsigned short* Ad2 = As + (d * 2) * 8192;         // buf of tile t+2
        unsigned short* Bd2 = Bs + (d * 2) * 8192;
        PHASE(d, 0, 0, 1,
              { STAGE(xAn + (size_t)128 * ND, Ad1 + 8192);
                STAGE(xBn + (size_t)128 * ND, Bd1 + 8192); }, {});
        PHASE(d, 0, 1, 0, {}, {});
        PHASE(d, 1, 0, 1, {}, {});
        PHASE(d, 1, 1, 0,
              { STAGE(xAnn, Ad2); STAGE(xBnn, Bd2); },
              { asm volatile("s_waitcnt vmcnt(4)" ::: "memory"); });
    }
    {   // t = NT-2 (d=0): stage only A1/B1 of last tile; drain before it
        const unsigned short* xAn = xA + (NT - 1) * 64;
        const unsigned short* xBn = xB + (NT - 1) * 64;
        PHASE(0, 0, 0, 1,
              { STAGE(xAn + (size_t)128 * ND, As + 3 * 8192);
                STAGE(xBn + (size_t)128 * ND, Bs + 3 * 8192); }, {});
        PHASE(0, 0, 1, 0, {}, {});
        PHASE(0, 1, 0, 1, {}, {});
        PHASE(0, 1, 1, 0, {}, { asm volatile("s_waitcnt vmcnt(0)" ::: "memory"); });
    }
    // t = NT-1 (d=1): pure compute
    PHASE(1, 0, 0, 1, {}, {});
    PHASE(1, 0, 1, 0, {}, {});
    PHASE(1, 1, 0, 1, {}, {});
    PHASE(1, 1, 1, 0, {}, {});

#undef PHASE
#undef STAGE

    // ---- epilogue: h[m,q] += relu(c1) @ w2, two 128-col passes reusing LDS
    unsigned short* c1s = SM;                      // [256][136] (69632 B)
    f32x4 hacc[2];
    hacc[0] = (f32x4){0.f, 0.f, 0.f, 0.f};
    hacc[1] = (f32x4){0.f, 0.f, 0.f, 0.f};

#pragma unroll
    for (int nu = 0; nu < 2; nu++) {
#pragma unroll
        for (int mi = 0; mi < 8; mi++) {
            const int row = (mi >> 2) * 128 + wm * 64 + (mi & 3) * 16 + quad * 4;
#pragma unroll
            for (int nj = 0; nj < 2; nj++) {
                const int col = wn * 32 + nj * 16 + lc;        // local 0..127
                const int ni = nu * 2 + nj;
#pragma unroll
                for (int r = 0; r < 4; r++)
                    c1s[(row + r) * 136 + col] = f2bf(fmaxf(acc[mi][ni][r], 0.f));
            }
        }
        asm volatile("s_waitcnt lgkmcnt(0)" ::: "memory");
        __builtin_amdgcn_s_barrier();
        asm volatile("" ::: "memory");
        // wave handles rows wv*32..+31; K = 128 local cols, hi+lo w2
#pragma unroll
        for (int ks = 0; ks < 4; ks++) {
            short8 bh = *(const short8*)&w2hi[lc * 264 + nu * 128 + ks * 32 + quad * 8];
            short8 bl = *(const short8*)&w2lo[lc * 264 + nu * 128 + ks * 32 + quad * 8];
#pragma unroll
            for (int mt = 0; mt < 2; mt++) {
                short8 afr = *(const short8*)&c1s[(wv * 32 + mt * 16 + lc) * 136 +
                                                  ks * 32 + quad * 8];
                hacc[mt] = __builtin_amdgcn_mfma_f32_16x16x32_bf16(afr, bh, hacc[mt], 0, 0, 0);
                hacc[mt] = __builtin_amdgcn_mfma_f32_16x16x32_bf16(afr, bl, hacc[mt], 0, 0, 0);
            }
        }
        asm volatile("" ::: "memory");
        __builtin_amdgcn_s_barrier();
        asm volatile("" ::: "memory");
    }

    if (lc < NH) {
        float* hp = h_part + (size_t)byn * (NN * NH);
#pragma unroll
        for (int mt = 0; mt < 2; mt++)
#pragma unroll
            for (int r = 0; r < 4; r++)
                hp[(size_t)(m0 + wv * 32 + mt * 16 + quad * 4 + r) * NH + lc] = hacc[mt][r];
    }
}

// --------- k_fuse v2: per-segment softmax (attn in LDS only) + gram + bdh +
// out_segment. 64 blocks x 512 threads. Phase B: 4 n-slots x 128 d-blocks,
// each thread owns 8 d-cols (ushort8/frame), acc[8][8] in regs; slot
// reduction reuses hl (attn dead by then; 128x64 floats = 32KB = hl exactly);
// bdh write is then a coalesced copy (hl linear layout == bdh[b] layout).
__global__ __launch_bounds__(512) void k_fuse(const float* __restrict__ h_part,
                                              const unsigned short* __restrict__ xb,
                                              const int* __restrict__ segoff,
                                              float* __restrict__ bdh,
                                              float* __restrict__ out_segment,
                                              float* __restrict__ gram) {
    const int b = blockIdx.x;
    const int s0 = segoff[b], s1 = segoff[b + 1];
    const int len = s1 - s0;
    const int tid = threadIdx.x;
    const int wv = tid >> 6;
    __shared__ float hl[1024 * NH];      // 32KB: h sums -> attn -> bdh partial
    __shared__ float xsl[4][1024];       // 16KB: per-slot x column sums
    __shared__ float red[8][NH];
    __shared__ float mb[NH];
    __shared__ float sinv[NH];
    __shared__ float gred[8][64];

    float mx[NH];
#pragma unroll
    for (int q = 0; q < NH; q++) mx[q] = -1e30f;

    // pass 1: sum planes -> hl, max   (len <= 1024 guaranteed; actual < 512)
    for (int n = s0 + tid; n < s1; n += 512) {
        float v[NH];
#pragma unroll
        for (int q = 0; q < NH; q++) v[q] = 0.f;
#pragma unroll
        for (int p = 0; p < NPL; p++) {
            const float4* hp = (const float4*)(h_part + (size_t)p * (NN * NH) + (size_t)n * NH);
            float4 u0 = hp[0], u1 = hp[1];
            v[0] += u0.x; v[1] += u0.y; v[2] += u0.z; v[3] += u0.w;
            v[4] += u1.x; v[5] += u1.y; v[6] += u1.z; v[7] += u1.w;
        }
#pragma unroll
        for (int q = 0; q < NH; q++) {
            hl[(n - s0) * NH + q] = v[q];
            mx[q] = fmaxf(mx[q], v[q]);
        }
    }
#pragma unroll
    for (int q = 0; q < NH; q++)
        for (int o = 1; o < 64; o <<= 1) mx[q] = fmaxf(mx[q], __shfl_xor(mx[q], o));
    if ((tid & 63) == 0)
        for (int q = 0; q < NH; q++) red[wv][q] = mx[q];
    __syncthreads();
    if (tid < NH) {
        float m = red[0][tid];
#pragma unroll
        for (int w = 1; w < 8; w++) m = fmaxf(m, red[w][tid]);
        mb[tid] = m;
    }
    __syncthreads();

    // pass 2: sum of exp (from hl)
    float sm[NH];
#pragma unroll
    for (int q = 0; q < NH; q++) sm[q] = 0.f;
    for (int n = s0 + tid; n < s1; n += 512) {
#pragma unroll
        for (int q = 0; q < NH; q++) sm[q] += expf(hl[(n - s0) * NH + q] - mb[q]);
    }
#pragma unroll
    for (int q = 0; q < NH; q++)
        for (int o = 1; o < 64; o <<= 1) sm[q] += __shfl_xor(sm[q], o);
    if ((tid & 63) == 0)
        for (int q = 0; q < NH; q++) red[wv][q] = sm[q];
    __syncthreads();
    if (tid < NH) {
        float s = red[0][tid];
#pragma unroll
        for (int w = 1; w < 8; w++) s += red[w][tid];
        sinv[tid] = 1.0f / s;
    }
    __syncthreads();

    // pass 3: attn in place + gram accumulate
    float g[NH][NH];
#pragma unroll
    for (int i = 0; i < NH; i++)
#pragma unroll
        for (int j = 0; j < NH; j++) g[i][j] = 0.f;

    for (int n = s0 + tid; n < s1; n += 512) {
        float a[NH];
#pragma unroll
        for (int q = 0; q < NH; q++) {
            a[q] = expf(hl[(n - s0) * NH + q] - mb[q]) * sinv[q];
            hl[(n - s0) * NH + q] = a[q];
        }
#pragma unroll
        for (int i = 0; i < NH; i++)
#pragma unroll
            for (int j = 0; j < NH; j++) g[i][j] += a[i] * a[j];
    }
#pragma unroll
    for (int i = 0; i < NH; i++)
#pragma unroll
        for (int j = 0; j < NH; j++)
            for (int o = 1; o < 64; o <<= 1) g[i][j] += __shfl_xor(g[i][j], o);
    if ((tid & 63) == 0) {
#pragma unroll
        for (int i = 0; i < NH; i++)
#pragma unroll
            for (int j = 0; j < NH; j++) gred[wv][i * NH + j] = g[i][j];
    }
    __syncthreads();                     // gred ready AND hl (attn) stable
    if (tid < 64) {
        float s = gred[0][tid];
#pragma unroll
        for (int w = 1; w < 8; w++) s += gred[w][tid];
        gram[(size_t)b * 64 + tid] = s;
    }

    // phase B: 4 slots x 128 d-blocks; acc[dd][q] += x[n, dl*8+dd]*attn[n,q]
    const int slot = tid >> 7;           // 0..3
    const int dl = tid & 127;            // d-block (8 cols)
    float acc[8][NH];
    float xs[8];
#pragma unroll
    for (int dd = 0; dd < 8; dd++) {
        xs[dd] = 0.f;
#pragma unroll
        for (int q = 0; q < NH; q++) acc[dd][q] = 0.f;
    }

    const unsigned short* xp = xb + (size_t)s0 * ND + dl * 8;
    for (int n = slot; n < len; n += 4) {
        ushort8 xv = *(const ushort8*)(xp + (size_t)n * ND);
        const float* ap = &hl[n * NH];
        float4 a0 = *(const float4*)ap;
        float4 a1 = *(const float4*)(ap + 4);
        float aq[NH] = {a0.x, a0.y, a0.z, a0.w, a1.x, a1.y, a1.z, a1.w};
#pragma unroll
        for (int dd = 0; dd < 8; dd++) {
            float xf = bf2f(xv[dd]);
            xs[dd] += xf;
#pragma unroll
            for (int q = 0; q < NH; q++) acc[dd][q] += xf * aq[q];
        }
    }
#pragma unroll
    for (int dd = 0; dd < 8; dd++) xsl[slot][dl * 8 + dd] = xs[dd];
    __syncthreads();                     // all slots done reading attn from hl

    // slot reduction into hl[dl*64 + dd*8 + q]  (layout == bdh[b] linear)
    if (slot == 0) {
#pragma unroll
        for (int dd = 0; dd < 8; dd++)
#pragma unroll
            for (int q = 0; q < NH; q++) hl[dl * 64 + dd * 8 + q] = acc[dd][q];
    }
    __syncthreads();
#pragma unroll
    for (int s = 1; s < 4; s++) {
        if (slot == s) {
#pragma unroll
            for (int dd = 0; dd < 8; dd++)
#pragma unroll
                for (int q = 0; q < NH; q++) hl[dl * 64 + dd * 8 + q] += acc[dd][q];
        }
        __syncthreads();
    }

    // coalesced bdh write + out_segment
    float4* bp = (float4*)(bdh + (size_t)b * (ND * NH));
    const float4* hp4 = (const float4*)hl;
    for (int i = tid; i < 2048; i += 512) bp[i] = hp4[i];
    const float il = 1.0f / (float)len;
    for (int d = tid; d < ND; d += 512) {
        float s = xsl[0][d] + xsl[1][d] + xsl[2][d] + xsl[3][d];
        out_segment[(size_t)b * ND + d] = s * il;
    }
}

// --------------- out_part[p] = bdh[64,8192] @ w_post chunk p  (split-K KSPL)
__global__ __launch_bounds__(256) void k_post(const float* __restrict__ bdh,
                                              const float* __restrict__ wp,
                                              float* __restrict__ out_part) {
    __shared__ float as[32][68];
    __shared__ float bs[32][128];
    const int tid = threadIdx.x;
    const int n0 = blockIdx.x * 128;
    const int k0 = blockIdx.y * (8192 / KSPL);
    const int tr = tid >> 4, tc = tid & 15;

    float acc[4][8];
#pragma unroll
    for (int i = 0; i < 4; i++)
#pragma unroll
        for (int j = 0; j < 8; j++) acc[i][j] = 0.f;

    for (int kc = 0; kc < 8192 / KSPL; kc += 32) {
        __syncthreads();
        {
            int r = tid >> 2;
            int c = (tid & 3) * 8;
            const float4* gp = (const float4*)(bdh + (size_t)r * (ND * NH) + k0 + kc + c);
            float4 v0 = gp[0], v1 = gp[1];
            as[c + 0][r] = v0.x; as[c + 1][r] = v0.y; as[c + 2][r] = v0.z; as[c + 3][r] = v0.w;
            as[c + 4][r] = v1.x; as[c + 5][r] = v1.y; as[c + 6][r] = v1.z; as[c + 7][r] = v1.w;
        }
        {
            int r = tid >> 3;
            int c = (tid & 7) * 16;
            const float4* gp = (const float4*)(wp + (size_t)(k0 + kc + r) * ND + n0 + c);
            float4* sp = (float4*)&bs[r][c];
            sp[0] = gp[0]; sp[1] = gp[1]; sp[2] = gp[2]; sp[3] = gp[3];
        }
        __syncthreads();
#pragma unroll
        for (int k = 0; k < 32; k++) {
            float4 a  = *(const float4*)&as[k][tr * 4];
            float4 b0 = *(const float4*)&bs[k][tc * 8];
            float4 b1 = *(const float4*)&bs[k][tc * 8 + 4];
            float av[4] = {a.x, a.y, a.z, a.w};
            float bv[8] = {b0.x, b0.y, b0.z, b0.w, b1.x, b1.y, b1.z, b1.w};
#pragma unroll
            for (int i = 0; i < 4; i++)
#pragma unroll
                for (int j = 0; j < 8; j++) acc[i][j] += av[i] * bv[j];
        }
    }

    float* op = out_part + (size_t)blockIdx.y * (NB * ND);
#pragma unroll
    for (int i = 0; i < 4; i++)
#pragma unroll
        for (int j = 0; j < 8; j++)
            op[(size_t)(tr * 4 + i) * ND + n0 + tc * 8 + j] = acc[i][j];
}

// ------------------------------------- out = sum over KSPL k-chunk partials
__global__ __launch_bounds__(256) void k_post_red(const float* __restrict__ out_part,
                                                  float* __restrict__ out) {
    const int i = (blockIdx.x * 256 + threadIdx.x) * 4;
    float4 s = *(const float4*)(out_part + i);
#pragma unroll
    for (int p = 1; p < KSPL; p++) {
        float4 v = *(const float4*)(out_part + (size_t)p * (NB * ND) + i);
        s.x += v.x; s.y += v.y; s.z += v.z; s.w += v.w;
    }
    *(float4*)(out + i) = s;
}

extern "C" void kernel_launch(void* const* d_in, const int* in_sizes, int n_in,
                              void* d_out, int out_size, void* d_ws, size_t ws_size,
                              hipStream_t stream) {
    (void)in_sizes; (void)n_in; (void)out_size; (void)ws_size;
    const float* x      = (const float*)d_in[0];
    const int*   segnum = (const int*)d_in[1];
    const float* w1     = (const float*)d_in[2];
    const float* w2     = (const float*)d_in[3];
    const float* wpost  = (const float*)d_in[4];

    float* out         = (float*)d_out;            // [64*1024]
    float* out_segment = out + NB * ND;            // [64*1024]
    float* gram        = out + 2 * NB * ND;        // [64*64]

    char* ws = (char*)d_ws;
    const size_t MB = 1024 * 1024;
    int*   segoff   = (int*)ws;                                    // 1KB   @0
    float* bdh      = (float*)(ws + 2 * MB);                       // 2MB   @2MB
    float* h_part   = (float*)(ws + 4 * MB);                       // 4MB   @4MB (8 planes)
    unsigned short* xb  = (unsigned short*)(ws + 12 * MB);         // 32MB  @12MB
    unsigned short* w1t = (unsigned short*)(ws + 44 * MB);         // 4MB   @44MB
    float* out_part  = (float*)(ws + 48 * MB);                     // 8MB   @48MB (KSPL=32)

    k_pre<<<10241, 256, 0, stream>>>(x, w1, segnum, xb, w1t, segoff);
    k_c1h<<<dim3(NN / 256, NA / 256), 512, 0, stream>>>(xb, w1t, w2, h_part);
    k_fuse<<<NB, 512, 0, stream>>>(h_part, xb, segoff, bdh, out_segment, gram);
    k_post<<<dim3(ND / 128, KSPL), 256, 0, stream>>>(bdh, wpost, out_part);
    k_post_red<<<(NB * ND) / (256 * 4), 256, 0, stream>>>(out_part, out);
}

// Round 8
// 275.121 us; speedup vs baseline: 1.4872x; 1.0314x over previous
//
#include <hip/hip_runtime.h>
#include <hip/hip_bf16.h>

// Problem dims (fixed by setup_inputs): B=64, N=16384, D=1024, A=2048, H=8
#define NB 64
#define NN 16384
#define ND 1024
#define NA 2048
#define NH 8
#define KSPL 32     // k_post split-K chunks
#define NPL 8       // h_part planes (= NA/256 n-blocks of k_c1h)
#define NT 16       // k_c1h K-tiles (ND/64)

typedef __attribute__((ext_vector_type(4))) float f32x4;
typedef __attribute__((ext_vector_type(8))) short short8;
typedef __attribute__((ext_vector_type(8))) unsigned short ushort8;

__device__ __forceinline__ unsigned short f2bf(float f) {
    unsigned int u = __float_as_uint(f);
    u = (u + 0x7fff + ((u >> 16) & 1)) >> 16;   // round-to-nearest-even
    return (unsigned short)u;
}

__device__ __forceinline__ float bf2f(unsigned short s) {
    return __uint_as_float((unsigned int)s << 16);
}

__device__ __forceinline__ void load_lds16(const void* g, void* l) {
    __builtin_amdgcn_global_load_lds((const __attribute__((address_space(1))) void*)g,
                                     (__attribute__((address_space(3))) void*)l, 16, 0, 0);
}

// ---- k_pre: segoff + cast x->xb + cast/transpose w1->w1t
__global__ __launch_bounds__(256) void k_pre(const float* __restrict__ x,
                                             const float* __restrict__ w1,
                                             const int* __restrict__ segnum,
                                             unsigned short* __restrict__ xb,
                                             unsigned short* __restrict__ w1t,
                                             int* __restrict__ segoff) {
    __shared__ unsigned short t[32][33];
    const int bx = blockIdx.x;
    if (bx < 8192) {
        size_t i = ((size_t)bx * 256 + threadIdx.x) * 8;
        float4 a = *(const float4*)(x + i);
        float4 b = *(const float4*)(x + i + 4);
        ushort8 o;
        o[0] = f2bf(a.x); o[1] = f2bf(a.y); o[2] = f2bf(a.z); o[3] = f2bf(a.w);
        o[4] = f2bf(b.x); o[5] = f2bf(b.y); o[6] = f2bf(b.z); o[7] = f2bf(b.w);
        *(ushort8*)(xb + i) = o;
    } else if (bx < 10240) {
        const int idx = bx - 8192;                 // 0..2047
        const int a0 = (idx & 63) * 32, d0 = (idx >> 6) * 32;
        const int tx = threadIdx.x & 31, ty4 = (threadIdx.x >> 5) * 4;
#pragma unroll
        for (int i = 0; i < 4; i++)
            t[tx][ty4 + i] = f2bf(w1[(size_t)(d0 + ty4 + i) * NA + a0 + tx]);
        __syncthreads();
#pragma unroll
        for (int i = 0; i < 4; i++)
            w1t[(size_t)(a0 + ty4 + i) * ND + d0 + tx] = t[ty4 + i][tx];
    } else {
        if (threadIdx.x == 0) {
            int a = 0;
            segoff[0] = 0;
            for (int b = 0; b < NB; b++) { a += segnum[b]; segoff[b + 1] = a; }
        }
    }
}

// --- k_c1h v3 (FROZEN; measured 72.4us twice): 256x256 tile, BK=64, 8 waves,
// 4-phase/K-tile, B frags register-resident (24 ds_read_b128/K-tile/wave).
// Hazard invariants as audited R1-R3. XCD-chunked swizzle (bijective, 512%8==0).
__global__ __launch_bounds__(512, 2) void k_c1h(const unsigned short* __restrict__ xb,
                                                const unsigned short* __restrict__ w1t,
                                                const float* __restrict__ w2,
                                                float* __restrict__ h_part) {
    __shared__ unsigned short SM[73984];           // 147968 B
    unsigned short* As   = SM;                     // [2 dbuf][2 half][128*64]
    unsigned short* Bs   = SM + 32768;             // same layout
    unsigned short* w2hi = SM + 65536;             // [16][264], rows 8..15 zero
    unsigned short* w2lo = SM + 69760;

    const int tid = threadIdx.x;
    const int wv = tid >> 6, lane = tid & 63;
    const int wm = wv >> 2, wn = wv & 3;           // 2 x 4 wave grid
    const int quad = lane >> 4, lc = lane & 15;
    const int l7 = lc & 7;

    const int wg = blockIdx.x + blockIdx.y * (NN / 256);
    const int swz = (wg & 7) * 64 + (wg >> 3);
    const int bxm = swz & 63, byn = swz >> 6;
    const int m0 = bxm * 256, n0 = byn * 256;

    // stage w2 slice -> transposed bf16 hi/lo planes [q][k], k in [0,256)
    for (int i = tid; i < 4224; i += 512) { w2hi[i] = 0; w2lo[i] = 0; }
    for (int i = tid; i < 2048; i += 512) {
        int k = i >> 3, q = i & 7;
        float w = w2[(size_t)(n0 + k) * NH + q];
        unsigned short hi = f2bf(w);
        w2hi[q * 264 + k] = hi;
        w2lo[q * 264 + k] = f2bf(w - bf2f(hi));
    }

    // staging constants: global source pre-swizzled, LDS linear (G21).
    const int rr = wv * 8 + (lane >> 3);
    const size_t goff0 = (size_t)rr * ND + (size_t)(((lane & 7) ^ (lane >> 3)) << 3);
    const size_t goff1 = goff0 + (size_t)64 * ND;  // j=1: rows +64
    const int ls0 = wv * 512, ls1 = (wv + 8) * 512;

    const unsigned short* xA = xb  + (size_t)m0 * ND;
    const unsigned short* xB = w1t + (size_t)n0 * ND;

#define STAGE(SRC, DST) do { \
        load_lds16((SRC) + goff0, (DST) + ls0); \
        load_lds16((SRC) + goff1, (DST) + ls1); } while (0)

    f32x4 acc[8][4];
#pragma unroll
    for (int i = 0; i < 8; i++)
#pragma unroll
        for (int j = 0; j < 4; j++) acc[i][j] = (f32x4){0.f, 0.f, 0.f, 0.f};

    // ds_read row offsets (row&7 == lc&7 for all fragments)
    int aoff[4], boff[2];
#pragma unroll
    for (int i = 0; i < 4; i++) aoff[i] = (wm * 64 + i * 16 + lc) * 64;
#pragma unroll
    for (int i = 0; i < 2; i++) boff[i] = (wn * 32 + i * 16 + lc) * 64;

    short8 bfr[4];   // B frags, register-resident across each (ks) phase pair

#define PHASE(D, KS, MU, LOADB, STAGES, WAIT2)                                   \
    do {                                                                         \
        const unsigned short* Ab = As + ((D) * 2 + (MU)) * 8192;                 \
        const unsigned short* Bb = Bs + ((D) * 2) * 8192;                        \
        const int kb = ((((KS) * 4) + quad) ^ l7) << 3;                          \
        short8 af[4];                                                            \
        _Pragma("unroll") for (int i = 0; i < 4; i++)                            \
            af[i] = *(const short8*)&Ab[aoff[i] + kb];                           \
        if (LOADB) {                                                             \
            _Pragma("unroll") for (int j = 0; j < 2; j++) {                      \
                bfr[j]     = *(const short8*)&Bb[boff[j] + kb];                  \
                bfr[2 + j] = *(const short8*)&Bb[8192 + boff[j] + kb];           \
            }                                                                    \
        }                                                                        \
        STAGES;                                                                  \
        asm volatile("" ::: "memory");                                           \
        __builtin_amdgcn_s_barrier();                                            \
        asm volatile("" ::: "memory");                                           \
        __builtin_amdgcn_s_setprio(1);                                           \
        _Pragma("unroll") for (int i = 0; i < 4; i++)                            \
            _Pragma("unroll") for (int j = 0; j < 4; j++)                        \
                acc[(MU) * 4 + i][j] = __builtin_amdgcn_mfma_f32_16x16x32_bf16(  \
                    af[i], bfr[j], acc[(MU) * 4 + i][j], 0, 0, 0);               \
        __builtin_amdgcn_s_setprio(0);                                           \
        WAIT2;                                                                   \
        asm volatile("" ::: "memory");                                           \
        __builtin_amdgcn_s_barrier();                                            \
        asm volatile("" ::: "memory");                                           \
    } while (0)

    // prologue: tile0 full (A0,B0,A1,B1) + tile1 A0,B0; allow newest 4 in flight
    STAGE(xA, As);                                  // A0(0)
    STAGE(xB, Bs);                                  // B0(0)
    STAGE(xA + (size_t)128 * ND, As + 8192);        // A1(0)
    STAGE(xB + (size_t)128 * ND, Bs + 8192);        // B1(0)
    STAGE(xA + 64, As + 16384);                     // A0(1)
    STAGE(xB + 64, Bs + 16384);                     // B0(1)
    asm volatile("s_waitcnt vmcnt(4)" ::: "memory");
    __builtin_amdgcn_s_barrier();
    asm volatile("" ::: "memory");

#pragma unroll 2
    for (int t = 0; t < NT - 2; t++) {
        const int d = t & 1;
        const unsigned short* xAn = xA + (t + 1) * 64;
        const unsigned short* xBn = xB + (t + 1) * 64;
        const unsigned short* xAnn = xA + (t + 2) * 64;
        const unsigned short* xBnn = xB + (t + 2) * 64;
        unsigned short* Ad1 = As + ((d ^ 1) * 2) * 8192;   // buf of tile t+1
        unsigned short* Bd1 = Bs + ((d ^ 1) * 2) * 8192;
        unsigned short* Ad2 = As + (d * 2) * 8192;         // buf of tile t+2
        unsigned short* Bd2 = Bs + (d * 2) * 8192;
        PHASE(d, 0, 0, 1,
              { STAGE(xAn + (size_t)128 * ND, Ad1 + 8192);
                STAGE(xBn + (size_t)128 * ND, Bd1 + 8192); }, {});
        PHASE(d, 0, 1, 0, {}, {});
        PHASE(d, 1, 0, 1, {}, {});
        PHASE(d, 1, 1, 0,
              { STAGE(xAnn, Ad2); STAGE(xBnn, Bd2); },
              { asm volatile("s_waitcnt vmcnt(4)" ::: "memory"); });
    }
    {   // t = NT-2 (d=0): stage only A1/B1 of last tile; drain before it
        const unsigned short* xAn = xA + (NT - 1) * 64;
        const unsigned short* xBn = xB + (NT - 1) * 64;
        PHASE(0, 0, 0, 1,
              { STAGE(xAn + (size_t)128 * ND, As + 3 * 8192);
                STAGE(xBn + (size_t)128 * ND, Bs + 3 * 8192); }, {});
        PHASE(0, 0, 1, 0, {}, {});
        PHASE(0, 1, 0, 1, {}, {});
        PHASE(0, 1, 1, 0, {}, { asm volatile("s_waitcnt vmcnt(0)" ::: "memory"); });
    }
    // t = NT-1 (d=1): pure compute
    PHASE(1, 0, 0, 1, {}, {});
    PHASE(1, 0, 1, 0, {}, {});
    PHASE(1, 1, 0, 1, {}, {});
    PHASE(1, 1, 1, 0, {}, {});

#undef PHASE
#undef STAGE

    // ---- epilogue: h[m,q] += relu(c1) @ w2, two 128-col passes reusing LDS
    unsigned short* c1s = SM;                      // [256][136] (69632 B)
    f32x4 hacc[2];
    hacc[0] = (f32x4){0.f, 0.f, 0.f, 0.f};
    hacc[1] = (f32x4){0.f, 0.f, 0.f, 0.f};

#pragma unroll
    for (int nu = 0; nu < 2; nu++) {
#pragma unroll
        for (int mi = 0; mi < 8; mi++) {
            const int row = (mi >> 2) * 128 + wm * 64 + (mi & 3) * 16 + quad * 4;
#pragma unroll
            for (int nj = 0; nj < 2; nj++) {
                const int col = wn * 32 + nj * 16 + lc;        // local 0..127
                const int ni = nu * 2 + nj;
#pragma unroll
                for (int r = 0; r < 4; r++)
                    c1s[(row + r) * 136 + col] = f2bf(fmaxf(acc[mi][ni][r], 0.f));
            }
        }
        asm volatile("s_waitcnt lgkmcnt(0)" ::: "memory");
        __builtin_amdgcn_s_barrier();
        asm volatile("" ::: "memory");
        // wave handles rows wv*32..+31; K = 128 local cols, hi+lo w2
#pragma unroll
        for (int ks = 0; ks < 4; ks++) {
            short8 bh = *(const short8*)&w2hi[lc * 264 + nu * 128 + ks * 32 + quad * 8];
            short8 bl = *(const short8*)&w2lo[lc * 264 + nu * 128 + ks * 32 + quad * 8];
#pragma unroll
            for (int mt = 0; mt < 2; mt++) {
                short8 afr = *(const short8*)&c1s[(wv * 32 + mt * 16 + lc) * 136 +
                                                  ks * 32 + quad * 8];
                hacc[mt] = __builtin_amdgcn_mfma_f32_16x16x32_bf16(afr, bh, hacc[mt], 0, 0, 0);
                hacc[mt] = __builtin_amdgcn_mfma_f32_16x16x32_bf16(afr, bl, hacc[mt], 0, 0, 0);
            }
        }
        asm volatile("" ::: "memory");
        __builtin_amdgcn_s_barrier();
        asm volatile("" ::: "memory");
    }

    if (lc < NH) {
        float* hp = h_part + (size_t)byn * (NN * NH);
#pragma unroll
        for (int mt = 0; mt < 2; mt++)
#pragma unroll
            for (int r = 0; r < 4; r++)
                hp[(size_t)(m0 + wv * 32 + mt * 16 + quad * 4 + r) * NH + lc] = hacc[mt][r];
    }
}

// --------- per-segment softmax -> attn (+gram fused); h = sum of NPL planes
__global__ __launch_bounds__(256) void k_attn(const float* __restrict__ h_part,
                                              float* __restrict__ attn,
                                              const int* __restrict__ segoff,
                                              float* __restrict__ gram) {
    const int b = blockIdx.x;
    const int s0 = segoff[b], s1 = segoff[b + 1];
    const int tid = threadIdx.x;
    const int wv = tid >> 6;
    __shared__ float hl[1024 * NH];      // 32KB cache of summed h (len <= 1024 always)
    __shared__ float red[4][NH];
    __shared__ float mb[NH];
    __shared__ float sinv[NH];
    __shared__ float gred[4][64];

    float mx[NH];
#pragma unroll
    for (int q = 0; q < NH; q++) mx[q] = -1e30f;

    // pass 1: sum planes -> hl + max
    for (int n = s0 + tid; n < s1; n += 256) {
        float v[NH];
#pragma unroll
        for (int q = 0; q < NH; q++) v[q] = 0.f;
#pragma unroll
        for (int p = 0; p < NPL; p++) {
            const float4* hp = (const float4*)(h_part + (size_t)p * (NN * NH) + (size_t)n * NH);
            float4 u0 = hp[0], u1 = hp[1];
            v[0] += u0.x; v[1] += u0.y; v[2] += u0.z; v[3] += u0.w;
            v[4] += u1.x; v[5] += u1.y; v[6] += u1.z; v[7] += u1.w;
        }
#pragma unroll
        for (int q = 0; q < NH; q++) {
            hl[(n - s0) * NH + q] = v[q];
            mx[q] = fmaxf(mx[q], v[q]);
        }
    }
#pragma unroll
    for (int q = 0; q < NH; q++)
        for (int o = 1; o < 64; o <<= 1) mx[q] = fmaxf(mx[q], __shfl_xor(mx[q], o));
    if ((tid & 63) == 0)
        for (int q = 0; q < NH; q++) red[wv][q] = mx[q];
    __syncthreads();
    if (tid < NH)
        mb[tid] = fmaxf(fmaxf(red[0][tid], red[1][tid]), fmaxf(red[2][tid], red[3][tid]));
    __syncthreads();

    // pass 2: sum of exp (from hl)
    float sm[NH];
#pragma unroll
    for (int q = 0; q < NH; q++) sm[q] = 0.f;
    for (int n = s0 + tid; n < s1; n += 256) {
#pragma unroll
        for (int q = 0; q < NH; q++) sm[q] += expf(hl[(n - s0) * NH + q] - mb[q]);
    }
#pragma unroll
    for (int q = 0; q < NH; q++)
        for (int o = 1; o < 64; o <<= 1) sm[q] += __shfl_xor(sm[q], o);
    if ((tid & 63) == 0)
        for (int q = 0; q < NH; q++) red[wv][q] = sm[q];
    __syncthreads();
    if (tid < NH)
        sinv[tid] = 1.0f / (red[0][tid] + red[1][tid] + red[2][tid] + red[3][tid]);
    __syncthreads();

    // pass 3: write attn + accumulate gram
    float g[NH][NH];
#pragma unroll
    for (int i = 0; i < NH; i++)
#pragma unroll
        for (int j = 0; j < NH; j++) g[i][j] = 0.f;

    for (int n = s0 + tid; n < s1; n += 256) {
        float a[NH];
        float* ar = &attn[(size_t)n * NH];
#pragma unroll
        for (int q = 0; q < NH; q++) {
            a[q] = expf(hl[(n - s0) * NH + q] - mb[q]) * sinv[q];
            ar[q] = a[q];
        }
#pragma unroll
        for (int i = 0; i < NH; i++)
#pragma unroll
            for (int j = 0; j < NH; j++) g[i][j] += a[i] * a[j];
    }
#pragma unroll
    for (int i = 0; i < NH; i++)
#pragma unroll
        for (int j = 0; j < NH; j++)
            for (int o = 1; o < 64; o <<= 1) g[i][j] += __shfl_xor(g[i][j], o);

    if ((tid & 63) == 0) {
#pragma unroll
        for (int i = 0; i < NH; i++)
#pragma unroll
            for (int j = 0; j < NH; j++) gred[wv][i * NH + j] = g[i][j];
    }
    __syncthreads();
    if (tid < 64)
        gram[(size_t)b * 64 + tid] = gred[0][tid] + gred[1][tid] + gred[2][tid] + gred[3][tid];
}

// ---- k_bdh (direct): grid (64 segs x 4 d-slices), 128 thr; thread owns 2
// d-cols for ALL frames of its segment -> block writes bdh[b, slice] and
// out_segment[b, slice] EXCLUSIVELY. No bdh_part, no reduction kernel.
// Wave load = 64 lanes x 4B contiguous (256B segment) per frame: coalesced.
__global__ __launch_bounds__(128) void k_bdh(const unsigned short* __restrict__ xb,
                                             const float* __restrict__ attn,
                                             const int* __restrict__ segoff,
                                             float* __restrict__ bdh,
                                             float* __restrict__ out_segment) {
    const int b = blockIdx.x;
    const int d0 = blockIdx.y * 256 + threadIdx.x * 2;   // 2 d-cols
    const int s0 = segoff[b], s1 = segoff[b + 1];
    const int len = s1 - s0;

    float acc0[NH], acc1[NH];
    float xs0 = 0.f, xs1 = 0.f;
#pragma unroll
    for (int q = 0; q < NH; q++) { acc0[q] = 0.f; acc1[q] = 0.f; }

    const unsigned short* xp = xb + (size_t)s0 * ND + d0;
    const float* ap = attn + (size_t)s0 * NH;
#pragma unroll 4
    for (int n = 0; n < len; n++) {
        unsigned int xv = *(const unsigned int*)(xp + (size_t)n * ND);
        float4 a0 = *(const float4*)(ap + (size_t)n * NH);
        float4 a1 = *(const float4*)(ap + (size_t)n * NH + 4);
        float x0 = bf2f((unsigned short)(xv & 0xffffu));
        float x1 = bf2f((unsigned short)(xv >> 16));
        xs0 += x0; xs1 += x1;
        float aq[NH] = {a0.x, a0.y, a0.z, a0.w, a1.x, a1.y, a1.z, a1.w};
#pragma unroll
        for (int q = 0; q < NH; q++) {
            acc0[q] += x0 * aq[q];
            acc1[q] += x1 * aq[q];
        }
    }
    float* bp = bdh + (size_t)b * (ND * NH) + (size_t)d0 * NH;
    *(float4*)(bp + 0)  = make_float4(acc0[0], acc0[1], acc0[2], acc0[3]);
    *(float4*)(bp + 4)  = make_float4(acc0[4], acc0[5], acc0[6], acc0[7]);
    *(float4*)(bp + 8)  = make_float4(acc1[0], acc1[1], acc1[2], acc1[3]);
    *(float4*)(bp + 12) = make_float4(acc1[4], acc1[5], acc1[6], acc1[7]);
    const float il = 1.0f / (float)len;
    out_segment[(size_t)b * ND + d0]     = xs0 * il;
    out_segment[(size_t)b * ND + d0 + 1] = xs1 * il;
}

// --------------- out_part[p] = bdh[64,8192] @ w_post chunk p  (split-K KSPL)
__global__ __launch_bounds__(256) void k_post(const float* __restrict__ bdh,
                                              const float* __restrict__ wp,
                                              float* __restrict__ out_part) {
    __shared__ float as[32][68];
    __shared__ float bs[32][128];
    const int tid = threadIdx.x;
    const int n0 = blockIdx.x * 128;
    const int k0 = blockIdx.y * (8192 / KSPL);
    const int tr = tid >> 4, tc = tid & 15;

    float acc[4][8];
#pragma unroll
    for (int i = 0; i < 4; i++)
#pragma unroll
        for (int j = 0; j < 8; j++) acc[i][j] = 0.f;

    for (int kc = 0; kc < 8192 / KSPL; kc += 32) {
        __syncthreads();
        {
            int r = tid >> 2;
            int c = (tid & 3) * 8;
            const float4* gp = (const float4*)(bdh + (size_t)r * (ND * NH) + k0 + kc + c);
            float4 v0 = gp[0], v1 = gp[1];
            as[c + 0][r] = v0.x; as[c + 1][r] = v0.y; as[c + 2][r] = v0.z; as[c + 3][r] = v0.w;
            as[c + 4][r] = v1.x; as[c + 5][r] = v1.y; as[c + 6][r] = v1.z; as[c + 7][r] = v1.w;
        }
        {
            int r = tid >> 3;
            int c = (tid & 7) * 16;
            const float4* gp = (const float4*)(wp + (size_t)(k0 + kc + r) * ND + n0 + c);
            float4* sp = (float4*)&bs[r][c];
            sp[0] = gp[0]; sp[1] = gp[1]; sp[2] = gp[2]; sp[3] = gp[3];
        }
        __syncthreads();
#pragma unroll
        for (int k = 0; k < 32; k++) {
            float4 a  = *(const float4*)&as[k][tr * 4];
            float4 b0 = *(const float4*)&bs[k][tc * 8];
            float4 b1 = *(const float4*)&bs[k][tc * 8 + 4];
            float av[4] = {a.x, a.y, a.z, a.w};
            float bv[8] = {b0.x, b0.y, b0.z, b0.w, b1.x, b1.y, b1.z, b1.w};
#pragma unroll
            for (int i = 0; i < 4; i++)
#pragma unroll
                for (int j = 0; j < 8; j++) acc[i][j] += av[i] * bv[j];
        }
    }

    float* op = out_part + (size_t)blockIdx.y * (NB * ND);
#pragma unroll
    for (int i = 0; i < 4; i++)
#pragma unroll
        for (int j = 0; j < 8; j++)
            op[(size_t)(tr * 4 + i) * ND + n0 + tc * 8 + j] = acc[i][j];
}

// ------------------------------------- out = sum over KSPL k-chunk partials
__global__ __launch_bounds__(256) void k_post_red(const float* __restrict__ out_part,
                                                  float* __restrict__ out) {
    const int i = (blockIdx.x * 256 + threadIdx.x) * 4;
    float4 s = *(const float4*)(out_part + i);
#pragma unroll
    for (int p = 1; p < KSPL; p++) {
        float4 v = *(const float4*)(out_part + (size_t)p * (NB * ND) + i);
        s.x += v.x; s.y += v.y; s.z += v.z; s.w += v.w;
    }
    *(float4*)(out + i) = s;
}

extern "C" void kernel_launch(void* const* d_in, const int* in_sizes, int n_in,
                              void* d_out, int out_size, void* d_ws, size_t ws_size,
                              hipStream_t stream) {
    (void)in_sizes; (void)n_in; (void)out_size; (void)ws_size;
    const float* x      = (const float*)d_in[0];
    const int*   segnum = (const int*)d_in[1];
    const float* w1     = (const float*)d_in[2];
    const float* w2     = (const float*)d_in[3];
    const float* wpost  = (const float*)d_in[4];

    float* out         = (float*)d_out;            // [64*1024]
    float* out_segment = out + NB * ND;            // [64*1024]
    float* gram        = out + 2 * NB * ND;        // [64*64]

    char* ws = (char*)d_ws;
    const size_t MB = 1024 * 1024;
    int*   segoff   = (int*)ws;                                    // 1KB   @0
    float* attn     = (float*)(ws + 1 * MB);                       // 512KB @1MB
    float* bdh      = (float*)(ws + 2 * MB);                       // 2MB   @2MB
    float* h_part   = (float*)(ws + 4 * MB);                       // 4MB   @4MB (8 planes)
    unsigned short* xb  = (unsigned short*)(ws + 12 * MB);         // 32MB  @12MB
    unsigned short* w1t = (unsigned short*)(ws + 44 * MB);         // 4MB   @44MB
    float* out_part  = (float*)(ws + 48 * MB);                     // 8MB   @48MB (KSPL=32)

    k_pre<<<10241, 256, 0, stream>>>(x, w1, segnum, xb, w1t, segoff);
    k_c1h<<<dim3(NN / 256, NA / 256), 512, 0, stream>>>(xb, w1t, w2, h_part);
    k_attn<<<NB, 256, 0, stream>>>(h_part, attn, segoff, gram);
    k_bdh<<<dim3(NB, 4), 128, 0, stream>>>(xb, attn, segoff, bdh, out_segment);
    k_post<<<dim3(ND / 128, KSPL), 256, 0, stream>>>(bdh, wpost, out_part);
    k_post_red<<<(NB * ND) / (256 * 4), 256, 0, stream>>>(out_part, out);
}

// Round 9
// 259.765 us; speedup vs baseline: 1.5751x; 1.0591x over previous
//
#include <hip/hip_runtime.h>
#include <hip/hip_bf16.h>

// Problem dims (fixed by setup_inputs): B=64, N=16384, D=1024, A=2048, H=8
#define NB 64
#define NN 16384
#define ND 1024
#define NA 2048
#define NH 8
#define NSLOT 8     // k_bdh frame-offset slots
#define KSPL 32     // k_post split-K chunks
#define NPL 8       // h_part planes (= NA/256 n-blocks of k_c1h)
#define NT 16       // k_c1h K-tiles (ND/64)

typedef __attribute__((ext_vector_type(4))) float f32x4;
typedef __attribute__((ext_vector_type(8))) short short8;
typedef __attribute__((ext_vector_type(8))) unsigned short ushort8;

__device__ __forceinline__ unsigned short f2bf(float f) {
    unsigned int u = __float_as_uint(f);
    u = (u + 0x7fff + ((u >> 16) & 1)) >> 16;   // round-to-nearest-even
    return (unsigned short)u;
}

__device__ __forceinline__ float bf2f(unsigned short s) {
    return __uint_as_float((unsigned int)s << 16);
}

__device__ __forceinline__ void load_lds16(const void* g, void* l) {
    __builtin_amdgcn_global_load_lds((const __attribute__((address_space(1))) void*)g,
                                     (__attribute__((address_space(3))) void*)l, 16, 0, 0);
}

// ---- k_pre: segoff + cast x->xb + cast/transpose w1->w1t
__global__ __launch_bounds__(256) void k_pre(const float* __restrict__ x,
                                             const float* __restrict__ w1,
                                             const int* __restrict__ segnum,
                                             unsigned short* __restrict__ xb,
                                             unsigned short* __restrict__ w1t,
                                             int* __restrict__ segoff) {
    __shared__ unsigned short t[32][33];
    const int bx = blockIdx.x;
    if (bx < 8192) {
        size_t i = ((size_t)bx * 256 + threadIdx.x) * 8;
        float4 a = *(const float4*)(x + i);
        float4 b = *(const float4*)(x + i + 4);
        ushort8 o;
        o[0] = f2bf(a.x); o[1] = f2bf(a.y); o[2] = f2bf(a.z); o[3] = f2bf(a.w);
        o[4] = f2bf(b.x); o[5] = f2bf(b.y); o[6] = f2bf(b.z); o[7] = f2bf(b.w);
        *(ushort8*)(xb + i) = o;
    } else if (bx < 10240) {
        const int idx = bx - 8192;                 // 0..2047
        const int a0 = (idx & 63) * 32, d0 = (idx >> 6) * 32;
        const int tx = threadIdx.x & 31, ty4 = (threadIdx.x >> 5) * 4;
#pragma unroll
        for (int i = 0; i < 4; i++)
            t[tx][ty4 + i] = f2bf(w1[(size_t)(d0 + ty4 + i) * NA + a0 + tx]);
        __syncthreads();
#pragma unroll
        for (int i = 0; i < 4; i++)
            w1t[(size_t)(a0 + ty4 + i) * ND + d0 + tx] = t[ty4 + i][tx];
    } else {
        if (threadIdx.x == 0) {
            int a = 0;
            segoff[0] = 0;
            for (int b = 0; b < NB; b++) { a += segnum[b]; segoff[b + 1] = a; }
        }
    }
}

// --- k_c1h v3-identity: v3 schedule (measured 72.3us) with IDENTITY block
// mapping (no XCD swizzle). R1/R4 measured identity -> FETCH 49.5MB vs 135MB
// with swizzle; this isolates swizzle-removal on the v3 schedule.
// 256x256 tile, BK=64, 8 waves (2Mx4N), 4-phase/K-tile, B frags
// register-resident (24 ds_read_b128/K-tile/wave). Hazard invariants R1-R3.
__global__ __launch_bounds__(512, 2) void k_c1h(const unsigned short* __restrict__ xb,
                                                const unsigned short* __restrict__ w1t,
                                                const float* __restrict__ w2,
                                                float* __restrict__ h_part) {
    __shared__ unsigned short SM[73984];           // 147968 B
    unsigned short* As   = SM;                     // [2 dbuf][2 half][128*64]
    unsigned short* Bs   = SM + 32768;             // same layout
    unsigned short* w2hi = SM + 65536;             // [16][264], rows 8..15 zero
    unsigned short* w2lo = SM + 69760;

    const int tid = threadIdx.x;
    const int wv = tid >> 6, lane = tid & 63;
    const int wm = wv >> 2, wn = wv & 3;           // 2 x 4 wave grid
    const int quad = lane >> 4, lc = lane & 15;
    const int l7 = lc & 7;
    const int m0 = blockIdx.x * 256, n0 = blockIdx.y * 256;

    // stage w2 slice -> transposed bf16 hi/lo planes [q][k], k in [0,256)
    for (int i = tid; i < 4224; i += 512) { w2hi[i] = 0; w2lo[i] = 0; }
    for (int i = tid; i < 2048; i += 512) {
        int k = i >> 3, q = i & 7;
        float w = w2[(size_t)(n0 + k) * NH + q];
        unsigned short hi = f2bf(w);
        w2hi[q * 264 + k] = hi;
        w2lo[q * 264 + k] = f2bf(w - bf2f(hi));
    }

    // staging constants: global source pre-swizzled, LDS linear (G21).
    const int rr = wv * 8 + (lane >> 3);
    const size_t goff0 = (size_t)rr * ND + (size_t)(((lane & 7) ^ (lane >> 3)) << 3);
    const size_t goff1 = goff0 + (size_t)64 * ND;  // j=1: rows +64
    const int ls0 = wv * 512, ls1 = (wv + 8) * 512;

    const unsigned short* xA = xb  + (size_t)m0 * ND;
    const unsigned short* xB = w1t + (size_t)n0 * ND;

#define STAGE(SRC, DST) do { \
        load_lds16((SRC) + goff0, (DST) + ls0); \
        load_lds16((SRC) + goff1, (DST) + ls1); } while (0)

    f32x4 acc[8][4];
#pragma unroll
    for (int i = 0; i < 8; i++)
#pragma unroll
        for (int j = 0; j < 4; j++) acc[i][j] = (f32x4){0.f, 0.f, 0.f, 0.f};

    // ds_read row offsets (row&7 == lc&7 for all fragments)
    int aoff[4], boff[2];
#pragma unroll
    for (int i = 0; i < 4; i++) aoff[i] = (wm * 64 + i * 16 + lc) * 64;
#pragma unroll
    for (int i = 0; i < 2; i++) boff[i] = (wn * 32 + i * 16 + lc) * 64;

    short8 bfr[4];   // B frags, register-resident across each (ks) phase pair

#define PHASE(D, KS, MU, LOADB, STAGES, WAIT2)                                   \
    do {                                                                         \
        const unsigned short* Ab = As + ((D) * 2 + (MU)) * 8192;                 \
        const unsigned short* Bb = Bs + ((D) * 2) * 8192;                        \
        const int kb = ((((KS) * 4) + quad) ^ l7) << 3;                          \
        short8 af[4];                                                            \
        _Pragma("unroll") for (int i = 0; i < 4; i++)                            \
            af[i] = *(const short8*)&Ab[aoff[i] + kb];                           \
        if (LOADB) {                                                             \
            _Pragma("unroll") for (int j = 0; j < 2; j++) {                      \
                bfr[j]     = *(const short8*)&Bb[boff[j] + kb];                  \
                bfr[2 + j] = *(const short8*)&Bb[8192 + boff[j] + kb];           \
            }                                                                    \
        }                                                                        \
        STAGES;                                                                  \
        asm volatile("" ::: "memory");                                           \
        __builtin_amdgcn_s_barrier();                                            \
        asm volatile("" ::: "memory");                                           \
        __builtin_amdgcn_s_setprio(1);                                           \
        _Pragma("unroll") for (int i = 0; i < 4; i++)                            \
            _Pragma("unroll") for (int j = 0; j < 4; j++)                        \
                acc[(MU) * 4 + i][j] = __builtin_amdgcn_mfma_f32_16x16x32_bf16(  \
                    af[i], bfr[j], acc[(MU) * 4 + i][j], 0, 0, 0);               \
        __builtin_amdgcn_s_setprio(0);                                           \
        WAIT2;                                                                   \
        asm volatile("" ::: "memory");                                           \
        __builtin_amdgcn_s_barrier();                                            \
        asm volatile("" ::: "memory");                                           \
    } while (0)

    // prologue: tile0 full (A0,B0,A1,B1) + tile1 A0,B0; allow newest 4 in flight
    STAGE(xA, As);                                  // A0(0)
    STAGE(xB, Bs);                                  // B0(0)
    STAGE(xA + (size_t)128 * ND, As + 8192);        // A1(0)
    STAGE(xB + (size_t)128 * ND, Bs + 8192);        // B1(0)
    STAGE(xA + 64, As + 16384);                     // A0(1)
    STAGE(xB + 64, Bs + 16384);                     // B0(1)
    asm volatile("s_waitcnt vmcnt(4)" ::: "memory");
    __builtin_amdgcn_s_barrier();
    asm volatile("" ::: "memory");

#pragma unroll 2
    for (int t = 0; t < NT - 2; t++) {
        const int d = t & 1;
        const unsigned short* xAn = xA + (t + 1) * 64;
        const unsigned short* xBn = xB + (t + 1) * 64;
        const unsigned short* xAnn = xA + (t + 2) * 64;
        const unsigned short* xBnn = xB + (t + 2) * 64;
        unsigned short* Ad1 = As + ((d ^ 1) * 2) * 8192;   // buf of tile t+1
        unsigned short* Bd1 = Bs + ((d ^ 1) * 2) * 8192;
        unsigned short* Ad2 = As + (d * 2) * 8192;         // buf of tile t+2
        unsigned short* Bd2 = Bs + (d * 2) * 8192;
        PHASE(d, 0, 0, 1,
              { STAGE(xAn + (size_t)128 * ND, Ad1 + 8192);
                STAGE(xBn + (size_t)128 * ND, Bd1 + 8192); }, {});
        PHASE(d, 0, 1, 0, {}, {});
        PHASE(d, 1, 0, 1, {}, {});
        PHASE(d, 1, 1, 0,
              { STAGE(xAnn, Ad2); STAGE(xBnn, Bd2); },
              { asm volatile("s_waitcnt vmcnt(4)" ::: "memory"); });
    }
    {   // t = NT-2 (d=0): stage only A1/B1 of last tile; drain before it
        const unsigned short* xAn = xA + (NT - 1) * 64;
        const unsigned short* xBn = xB + (NT - 1) * 64;
        PHASE(0, 0, 0, 1,
              { STAGE(xAn + (size_t)128 * ND, As + 3 * 8192);
                STAGE(xBn + (size_t)128 * ND, Bs + 3 * 8192); }, {});
        PHASE(0, 0, 1, 0, {}, {});
        PHASE(0, 1, 0, 1, {}, {});
        PHASE(0, 1, 1, 0, {}, { asm volatile("s_waitcnt vmcnt(0)" ::: "memory"); });
    }
    // t = NT-1 (d=1): pure compute
    PHASE(1, 0, 0, 1, {}, {});
    PHASE(1, 0, 1, 0, {}, {});
    PHASE(1, 1, 0, 1, {}, {});
    PHASE(1, 1, 1, 0, {}, {});

#undef PHASE
#undef STAGE

    // ---- epilogue: h[m,q] += relu(c1) @ w2, two 128-col passes reusing LDS
    unsigned short* c1s = SM;                      // [256][136] (69632 B)
    f32x4 hacc[2];
    hacc[0] = (f32x4){0.f, 0.f, 0.f, 0.f};
    hacc[1] = (f32x4){0.f, 0.f, 0.f, 0.f};

#pragma unroll
    for (int nu = 0; nu < 2; nu++) {
#pragma unroll
        for (int mi = 0; mi < 8; mi++) {
            const int row = (mi >> 2) * 128 + wm * 64 + (mi & 3) * 16 + quad * 4;
#pragma unroll
            for (int nj = 0; nj < 2; nj++) {
                const int col = wn * 32 + nj * 16 + lc;        // local 0..127
                const int ni = nu * 2 + nj;
#pragma unroll
                for (int r = 0; r < 4; r++)
                    c1s[(row + r) * 136 + col] = f2bf(fmaxf(acc[mi][ni][r], 0.f));
            }
        }
        asm volatile("s_waitcnt lgkmcnt(0)" ::: "memory");
        __builtin_amdgcn_s_barrier();
        asm volatile("" ::: "memory");
        // wave handles rows wv*32..+31; K = 128 local cols, hi+lo w2
#pragma unroll
        for (int ks = 0; ks < 4; ks++) {
            short8 bh = *(const short8*)&w2hi[lc * 264 + nu * 128 + ks * 32 + quad * 8];
            short8 bl = *(const short8*)&w2lo[lc * 264 + nu * 128 + ks * 32 + quad * 8];
#pragma unroll
            for (int mt = 0; mt < 2; mt++) {
                short8 afr = *(const short8*)&c1s[(wv * 32 + mt * 16 + lc) * 136 +
                                                  ks * 32 + quad * 8];
                hacc[mt] = __builtin_amdgcn_mfma_f32_16x16x32_bf16(afr, bh, hacc[mt], 0, 0, 0);
                hacc[mt] = __builtin_amdgcn_mfma_f32_16x16x32_bf16(afr, bl, hacc[mt], 0, 0, 0);
            }
        }
        asm volatile("" ::: "memory");
        __builtin_amdgcn_s_barrier();
        asm volatile("" ::: "memory");
    }

    if (lc < NH) {
        float* hp = h_part + (size_t)blockIdx.y * (NN * NH);
#pragma unroll
        for (int mt = 0; mt < 2; mt++)
#pragma unroll
            for (int r = 0; r < 4; r++)
                hp[(size_t)(m0 + wv * 32 + mt * 16 + quad * 4 + r) * NH + lc] = hacc[mt][r];
    }
}

// --------- per-segment softmax -> attn (+gram fused); h = sum of NPL planes
__global__ __launch_bounds__(256) void k_attn(const float* __restrict__ h_part,
                                              float* __restrict__ attn,
                                              const int* __restrict__ segoff,
                                              float* __restrict__ gram) {
    const int b = blockIdx.x;
    const int s0 = segoff[b], s1 = segoff[b + 1];
    const int tid = threadIdx.x;
    const int wv = tid >> 6;
    __shared__ float hl[1024 * NH];      // 32KB cache of summed h (len <= 1024 always)
    __shared__ float red[4][NH];
    __shared__ float mb[NH];
    __shared__ float sinv[NH];
    __shared__ float gred[4][64];

    float mx[NH];
#pragma unroll
    for (int q = 0; q < NH; q++) mx[q] = -1e30f;

    // pass 1: sum planes -> hl + max
    for (int n = s0 + tid; n < s1; n += 256) {
        float v[NH];
#pragma unroll
        for (int q = 0; q < NH; q++) v[q] = 0.f;
#pragma unroll
        for (int p = 0; p < NPL; p++) {
            const float4* hp = (const float4*)(h_part + (size_t)p * (NN * NH) + (size_t)n * NH);
            float4 u0 = hp[0], u1 = hp[1];
            v[0] += u0.x; v[1] += u0.y; v[2] += u0.z; v[3] += u0.w;
            v[4] += u1.x; v[5] += u1.y; v[6] += u1.z; v[7] += u1.w;
        }
#pragma unroll
        for (int q = 0; q < NH; q++) {
            hl[(n - s0) * NH + q] = v[q];
            mx[q] = fmaxf(mx[q], v[q]);
        }
    }
#pragma unroll
    for (int q = 0; q < NH; q++)
        for (int o = 1; o < 64; o <<= 1) mx[q] = fmaxf(mx[q], __shfl_xor(mx[q], o));
    if ((tid & 63) == 0)
        for (int q = 0; q < NH; q++) red[wv][q] = mx[q];
    __syncthreads();
    if (tid < NH)
        mb[tid] = fmaxf(fmaxf(red[0][tid], red[1][tid]), fmaxf(red[2][tid], red[3][tid]));
    __syncthreads();

    // pass 2: sum of exp (from hl)
    float sm[NH];
#pragma unroll
    for (int q = 0; q < NH; q++) sm[q] = 0.f;
    for (int n = s0 + tid; n < s1; n += 256) {
#pragma unroll
        for (int q = 0; q < NH; q++) sm[q] += expf(hl[(n - s0) * NH + q] - mb[q]);
    }
#pragma unroll
    for (int q = 0; q < NH; q++)
        for (int o = 1; o < 64; o <<= 1) sm[q] += __shfl_xor(sm[q], o);
    if ((tid & 63) == 0)
        for (int q = 0; q < NH; q++) red[wv][q] = sm[q];
    __syncthreads();
    if (tid < NH)
        sinv[tid] = 1.0f / (red[0][tid] + red[1][tid] + red[2][tid] + red[3][tid]);
    __syncthreads();

    // pass 3: write attn + accumulate gram
    float g[NH][NH];
#pragma unroll
    for (int i = 0; i < NH; i++)
#pragma unroll
        for (int j = 0; j < NH; j++) g[i][j] = 0.f;

    for (int n = s0 + tid; n < s1; n += 256) {
        float a[NH];
        float* ar = &attn[(size_t)n * NH];
#pragma unroll
        for (int q = 0; q < NH; q++) {
            a[q] = expf(hl[(n - s0) * NH + q] - mb[q]) * sinv[q];
            ar[q] = a[q];
        }
#pragma unroll
        for (int i = 0; i < NH; i++)
#pragma unroll
            for (int j = 0; j < NH; j++) g[i][j] += a[i] * a[j];
    }
#pragma unroll
    for (int i = 0; i < NH; i++)
#pragma unroll
        for (int j = 0; j < NH; j++)
            for (int o = 1; o < 64; o <<= 1) g[i][j] += __shfl_xor(g[i][j], o);

    if ((tid & 63) == 0) {
#pragma unroll
        for (int i = 0; i < NH; i++)
#pragma unroll
            for (int j = 0; j < NH; j++) gred[wv][i * NH + j] = g[i][j];
    }
    __syncthreads();
    if (tid < 64)
        gram[(size_t)b * 64 + tid] = gred[0][tid] + gred[1][tid] + gred[2][tid] + gred[3][tid];
}

// ---- bdh_part[slot][b][d][h] partial of sum_n x[n,d]*attn[n,h]; + xsum partial
// grid (NSLOT slots, 64 segs), block 128: thread owns 8 d-cols (ushort8/frame)
__global__ __launch_bounds__(128) void k_bdh(const unsigned short* __restrict__ xb,
                                             const float* __restrict__ attn,
                                             const int* __restrict__ segoff,
                                             float* __restrict__ bdh_part,
                                             float* __restrict__ xsum_part) {
    const int slot = blockIdx.x;          // 0..NSLOT-1
    const int b = blockIdx.y;
    const int s0 = segoff[b], s1 = segoff[b + 1];
    const int dl = threadIdx.x;           // 0..127 -> d = dl*8..dl*8+7

    float acc[8][NH];
    float xs[8];
#pragma unroll
    for (int dd = 0; dd < 8; dd++) {
        xs[dd] = 0.f;
#pragma unroll
        for (int q = 0; q < NH; q++) acc[dd][q] = 0.f;
    }

    for (int n = s0 + slot; n < s1; n += NSLOT) {
        ushort8 xv = *(const ushort8*)(xb + (size_t)n * ND + dl * 8);
        const float4* ap = (const float4*)&attn[(size_t)n * NH];
        float4 a0 = ap[0], a1 = ap[1];
        float aq[NH] = {a0.x, a0.y, a0.z, a0.w, a1.x, a1.y, a1.z, a1.w};
#pragma unroll
        for (int dd = 0; dd < 8; dd++) {
            float xf = bf2f(xv[dd]);
            xs[dd] += xf;
#pragma unroll
            for (int q = 0; q < NH; q++) acc[dd][q] += xf * aq[q];
        }
    }

    float* bp = bdh_part + ((size_t)slot * NB + b) * (ND * NH) + (size_t)dl * 64;
#pragma unroll
    for (int dd = 0; dd < 8; dd++) {
        *(float4*)(bp + dd * 8)     = make_float4(acc[dd][0], acc[dd][1], acc[dd][2], acc[dd][3]);
        *(float4*)(bp + dd * 8 + 4) = make_float4(acc[dd][4], acc[dd][5], acc[dd][6], acc[dd][7]);
    }
    float* xp = xsum_part + ((size_t)slot * NB + b) * ND + (size_t)dl * 8;
    *(float4*)(xp)     = make_float4(xs[0], xs[1], xs[2], xs[3]);
    *(float4*)(xp + 4) = make_float4(xs[4], xs[5], xs[6], xs[7]);
}

// ------------- reduce NSLOT slots -> bdh fp32 [64][8192]; out_segment = mean(x)
__global__ __launch_bounds__(256) void k_bdh_red(const float* __restrict__ bdh_part,
                                                 const float* __restrict__ xsum_part,
                                                 const int* __restrict__ segoff,
                                                 float* __restrict__ bdh,
                                                 float* __restrict__ out_segment) {
    const int gid = blockIdx.x * 256 + threadIdx.x;   // 0..65535
    const int b = gid >> 10, d = gid & 1023;
    float4 sa = make_float4(0.f, 0.f, 0.f, 0.f);
    float4 sb = make_float4(0.f, 0.f, 0.f, 0.f);
    float xsum = 0.f;
#pragma unroll
    for (int s = 0; s < NSLOT; s++) {
        const float* p = bdh_part + ((size_t)s * NB + b) * (ND * NH) + (size_t)d * NH;
        float4 u = ((const float4*)p)[0], v = ((const float4*)p)[1];
        sa.x += u.x; sa.y += u.y; sa.z += u.z; sa.w += u.w;
        sb.x += v.x; sb.y += v.y; sb.z += v.z; sb.w += v.w;
        xsum += xsum_part[((size_t)s * NB + b) * ND + d];
    }
    float* bp = bdh + (size_t)b * (ND * NH) + (size_t)d * NH;
    ((float4*)bp)[0] = sa;
    ((float4*)bp)[1] = sb;
    const int len = segoff[b + 1] - segoff[b];
    out_segment[(size_t)b * ND + d] = xsum / (float)len;
}

// --------------- out_part[p] = bdh[64,8192] @ w_post chunk p  (split-K KSPL)
__global__ __launch_bounds__(256) void k_post(const float* __restrict__ bdh,
                                              const float* __restrict__ wp,
                                              float* __restrict__ out_part) {
    __shared__ float as[32][68];
    __shared__ float bs[32][128];
    const int tid = threadIdx.x;
    const int n0 = blockIdx.x * 128;
    const int k0 = blockIdx.y * (8192 / KSPL);
    const int tr = tid >> 4, tc = tid & 15;

    float acc[4][8];
#pragma unroll
    for (int i = 0; i < 4; i++)
#pragma unroll
        for (int j = 0; j < 8; j++) acc[i][j] = 0.f;

    for (int kc = 0; kc < 8192 / KSPL; kc += 32) {
        __syncthreads();
        {
            int r = tid >> 2;
            int c = (tid & 3) * 8;
            const float4* gp = (const float4*)(bdh + (size_t)r * (ND * NH) + k0 + kc + c);
            float4 v0 = gp[0], v1 = gp[1];
            as[c + 0][r] = v0.x; as[c + 1][r] = v0.y; as[c + 2][r] = v0.z; as[c + 3][r] = v0.w;
            as[c + 4][r] = v1.x; as[c + 5][r] = v1.y; as[c + 6][r] = v1.z; as[c + 7][r] = v1.w;
        }
        {
            int r = tid >> 3;
            int c = (tid & 7) * 16;
            const float4* gp = (const float4*)(wp + (size_t)(k0 + kc + r) * ND + n0 + c);
            float4* sp = (float4*)&bs[r][c];
            sp[0] = gp[0]; sp[1] = gp[1]; sp[2] = gp[2]; sp[3] = gp[3];
        }
        __syncthreads();
#pragma unroll
        for (int k = 0; k < 32; k++) {
            float4 a  = *(const float4*)&as[k][tr * 4];
            float4 b0 = *(const float4*)&bs[k][tc * 8];
            float4 b1 = *(const float4*)&bs[k][tc * 8 + 4];
            float av[4] = {a.x, a.y, a.z, a.w};
            float bv[8] = {b0.x, b0.y, b0.z, b0.w, b1.x, b1.y, b1.z, b1.w};
#pragma unroll
            for (int i = 0; i < 4; i++)
#pragma unroll
                for (int j = 0; j < 8; j++) acc[i][j] += av[i] * bv[j];
        }
    }

    float* op = out_part + (size_t)blockIdx.y * (NB * ND);
#pragma unroll
    for (int i = 0; i < 4; i++)
#pragma unroll
        for (int j = 0; j < 8; j++)
            op[(size_t)(tr * 4 + i) * ND + n0 + tc * 8 + j] = acc[i][j];
}

// ------------------------------------- out = sum over KSPL k-chunk partials
__global__ __launch_bounds__(256) void k_post_red(const float* __restrict__ out_part,
                                                  float* __restrict__ out) {
    const int i = (blockIdx.x * 256 + threadIdx.x) * 4;
    float4 s = *(const float4*)(out_part + i);
#pragma unroll
    for (int p = 1; p < KSPL; p++) {
        float4 v = *(const float4*)(out_part + (size_t)p * (NB * ND) + i);
        s.x += v.x; s.y += v.y; s.z += v.z; s.w += v.w;
    }
    *(float4*)(out + i) = s;
}

extern "C" void kernel_launch(void* const* d_in, const int* in_sizes, int n_in,
                              void* d_out, int out_size, void* d_ws, size_t ws_size,
                              hipStream_t stream) {
    (void)in_sizes; (void)n_in; (void)out_size; (void)ws_size;
    const float* x      = (const float*)d_in[0];
    const int*   segnum = (const int*)d_in[1];
    const float* w1     = (const float*)d_in[2];
    const float* w2     = (const float*)d_in[3];
    const float* wpost  = (const float*)d_in[4];

    float* out         = (float*)d_out;            // [64*1024]
    float* out_segment = out + NB * ND;            // [64*1024]
    float* gram        = out + 2 * NB * ND;        // [64*64]

    char* ws = (char*)d_ws;
    const size_t MB = 1024 * 1024;
    int*   segoff   = (int*)ws;                                    // 1KB   @0
    float* attn     = (float*)(ws + 1 * MB);                       // 512KB @1MB
    float* bdh      = (float*)(ws + 2 * MB);                       // 2MB   @2MB
    float* h_part   = (float*)(ws + 4 * MB);                       // 4MB   @4MB (8 planes)
    unsigned short* xb  = (unsigned short*)(ws + 12 * MB);         // 32MB  @12MB
    unsigned short* w1t = (unsigned short*)(ws + 44 * MB);         // 4MB   @44MB
    float* bdh_part  = (float*)(ws + 48 * MB);                     // 16MB  @48MB (NSLOT=8)
    float* xsum_part = (float*)(ws + 80 * MB);                     // 2MB   @80MB
    float* out_part  = (float*)(ws + 84 * MB);                     // 8MB   @84MB (KSPL=32)

    k_pre<<<10241, 256, 0, stream>>>(x, w1, segnum, xb, w1t, segoff);
    k_c1h<<<dim3(NN / 256, NA / 256), 512, 0, stream>>>(xb, w1t, w2, h_part);
    k_attn<<<NB, 256, 0, stream>>>(h_part, attn, segoff, gram);
    k_bdh<<<dim3(NSLOT, NB), 128, 0, stream>>>(xb, attn, segoff, bdh_part, xsum_part);
    k_bdh_red<<<256, 256, 0, stream>>>(bdh_part, xsum_part, segoff, bdh, out_segment);
    k_post<<<dim3(ND / 128, KSPL), 256, 0, stream>>>(bdh, wpost, out_part);
    k_post_red<<<(NB * ND) / (256 * 4), 256, 0, stream>>>(out_part, out);
}